// Round 7
// baseline (8984.405 us; speedup 1.0000x reference)
//
#include <hip/hip_runtime.h>
#include <math.h>

typedef __attribute__((ext_vector_type(8))) short short8;
typedef __attribute__((ext_vector_type(4))) float f32x4;

#define TSTEPS 1024
#define BATCH  64
#define CDIM   512
#define NGATE  2048

// ---- workspace layout ----
#define XG_BYTES ((size_t)TSTEPS * BATCH * NGATE * 2)   // 256 MiB bf16
#define HEX_OFF  XG_BYTES
// hex: u32 [phase][bg][row][c] tagged words = 2*4*16*512*4 = 256 KiB
#define HEX_BYTES (2 * 4 * 16 * 512 * 4)
#define CNT_OFF  (HEX_OFF + HEX_BYTES)   // election/consensus/test region, 1 KiB
#define WS_NEED  (CNT_OFF + 1024)

// ---- sequential kernel geometry: 256 blocks, 64 workers (4 bg x 16 cg) ----
#define SEQ_BLOCKS  256
#define SEQ_THREADS 512
#define SMEM_BYTES  98304   // pad to force 1 block/CU -> full co-residency
#define HA_OFF 0            // 2 x (16 x 512 bf16 swizzled) = 32768 (double buffer)
#define RM_OFF 32768        // 1024 u64 reset bitmask = 8192

// s_getreg imm for HW_REG_XCC_ID (id=20, offset=0, size=32): ((32-1)<<11)|20
#define XCC_GETREG_IMM 63508

__device__ __forceinline__ unsigned short f2bf(float x) {
  unsigned u = __builtin_bit_cast(unsigned, x);
  unsigned r = (u + 0x7FFFu + ((u >> 16) & 1u)) >> 16;
  return (unsigned short)r;
}
__device__ __forceinline__ float bf2f(unsigned short b) {
  unsigned u = ((unsigned)b) << 16;
  return __builtin_bit_cast(float, u);
}
__device__ __forceinline__ short8 pack8(float4 lo, float4 hi) {
  short8 r;
  r[0] = (short)f2bf(lo.x); r[1] = (short)f2bf(lo.y);
  r[2] = (short)f2bf(lo.z); r[3] = (short)f2bf(lo.w);
  r[4] = (short)f2bf(hi.x); r[5] = (short)f2bf(hi.y);
  r[6] = (short)f2bf(hi.z); r[7] = (short)f2bf(hi.w);
  return r;
}
__device__ __forceinline__ float sigm(float z) { return 1.0f / (1.0f + expf(-z)); }

// ---- sc0 (XCD-L2-scope) primitives, used ONLY after the functional test ----
__device__ __forceinline__ void st_sc0_u32(unsigned* p, unsigned v) {
  asm volatile("global_store_dword %0, %1, off sc0" ::"v"(p), "v"(v) : "memory");
}
__device__ __forceinline__ unsigned ld_sc0_u32(const unsigned* p) {
  unsigned v;
  asm volatile("global_load_dword %0, %1, off sc0\n\ts_waitcnt vmcnt(0)"
               : "=&v"(v) : "v"(p) : "memory");
  return v;
}
__device__ __forceinline__ void ld8_sc0(const char* base, unsigned long long& v0,
                                        unsigned long long& v1, unsigned long long& v2,
                                        unsigned long long& v3, unsigned long long& v4,
                                        unsigned long long& v5, unsigned long long& v6,
                                        unsigned long long& v7) {
  asm volatile(
      "global_load_dwordx2 %0, %8, off sc0\n\t"
      "global_load_dwordx2 %1, %8, off offset:256 sc0\n\t"
      "global_load_dwordx2 %2, %8, off offset:512 sc0\n\t"
      "global_load_dwordx2 %3, %8, off offset:768 sc0\n\t"
      "global_load_dwordx2 %4, %8, off offset:1024 sc0\n\t"
      "global_load_dwordx2 %5, %8, off offset:1280 sc0\n\t"
      "global_load_dwordx2 %6, %8, off offset:1536 sc0\n\t"
      "global_load_dwordx2 %7, %8, off offset:1792 sc0\n\t"
      "s_waitcnt vmcnt(0)"
      : "=&v"(v0), "=&v"(v1), "=&v"(v2), "=&v"(v3),
        "=&v"(v4), "=&v"(v5), "=&v"(v6), "=&v"(v7)
      : "v"(base)
      : "memory");
}

// ============ kernel 1: xg[t,b,n] = x[t,b,:]@W_ih[n,:] + bih[n]+bhh[n] ======
__global__ __launch_bounds__(256, 2) void xg_prepass(
    const float* __restrict__ x, const float* __restrict__ wih,
    const float* __restrict__ bih, const float* __restrict__ bhh,
    unsigned short* __restrict__ xg) {
  __shared__ __align__(16) char lds[32768];
  char* Al = lds;
  char* Bl = lds + 16384;
  const int tid = threadIdx.x;
  const int bid = blockIdx.x;
  const int bm = bid & 511, bn = bid >> 9;
  const int lane = tid & 63, wv = tid >> 6;
  const int wm = wv >> 1, wn = wv & 1;
  const int grp = lane >> 4, lr = lane & 15;

  f32x4 acc[4][4] = {};
  float bsum[4];
#pragma unroll
  for (int nt = 0; nt < 4; ++nt) {
    int n = bn * 128 + wn * 64 + nt * 16 + lr;
    bsum[nt] = bih[n] + bhh[n];
  }

  for (int kb = 0; kb < 8; ++kb) {
    __syncthreads();
#pragma unroll
    for (int c = 0; c < 4; ++c) {
      int gi = tid + c * 256;
      int row = gi >> 3, colc = (gi & 7) * 8;
      const float* sA = x + ((size_t)(bm * 128 + row)) * 512 + kb * 64 + colc;
      float4 lo = *(const float4*)sA, hi = *(const float4*)(sA + 4);
      *(short8*)(Al + row * 128 + ((colc * 2) ^ ((row & 7) << 4))) = pack8(lo, hi);
      const float* sB = wih + ((size_t)(bn * 128 + row)) * 512 + kb * 64 + colc;
      float4 lo2 = *(const float4*)sB, hi2 = *(const float4*)(sB + 4);
      *(short8*)(Bl + row * 128 + ((colc * 2) ^ ((row & 7) << 4))) = pack8(lo2, hi2);
    }
    __syncthreads();
#pragma unroll
    for (int kk = 0; kk < 2; ++kk) {
      short8 af[4], bf[4];
#pragma unroll
      for (int mt = 0; mt < 4; ++mt) {
        int r = wm * 64 + mt * 16 + lr;
        af[mt] = *(const short8*)(Al + r * 128 + ((kk * 64 + grp * 16) ^ ((r & 7) << 4)));
      }
#pragma unroll
      for (int nt = 0; nt < 4; ++nt) {
        int r = wn * 64 + nt * 16 + lr;
        bf[nt] = *(const short8*)(Bl + r * 128 + ((kk * 64 + grp * 16) ^ ((r & 7) << 4)));
      }
#pragma unroll
      for (int mt = 0; mt < 4; ++mt)
#pragma unroll
        for (int nt = 0; nt < 4; ++nt)
          acc[mt][nt] = __builtin_amdgcn_mfma_f32_16x16x32_bf16(af[mt], bf[nt],
                                                                acc[mt][nt], 0, 0, 0);
    }
  }
#pragma unroll
  for (int mt = 0; mt < 4; ++mt)
#pragma unroll
    for (int nt = 0; nt < 4; ++nt)
#pragma unroll
      for (int q = 0; q < 4; ++q) {
        int m = bm * 128 + wm * 64 + mt * 16 + grp * 4 + q;
        int n = bn * 128 + wn * 64 + nt * 16 + lr;
        xg[(size_t)m * NGATE + n] = f2bf(acc[mt][nt][q] + bsum[nt]);
      }
}

// ============ kernel 2: persistent sequential LSTM ==========================
// h exchange word: (h_bf16 << 16) | step_tag. Transport chosen at runtime:
// sc0 (XCD-local L2) iff a bounded functional test passes on ALL workers;
// otherwise the proven agent-scope (sc1/MALL) path. Output identical.
__global__ __launch_bounds__(SEQ_THREADS, 1) void rlstm_seq(
    const void* __restrict__ rst, const float* __restrict__ h0,
    const float* __restrict__ c0, const float* __restrict__ whh,
    float* __restrict__ y, const unsigned short* __restrict__ xg,
    unsigned* __restrict__ hex, unsigned* __restrict__ cnt) {
  extern __shared__ __align__(16) char smem[];
  unsigned long long* RM = (unsigned long long*)(smem + RM_OFF);
  __shared__ int s_role, s_sc0;

  const int tid = threadIdx.x;

  // ---- hang-proof role election ----
  // cnt[0..7]: per-claimed-XCD rank; [8] ok votes; [9] vote count;
  // [10] stage2 rank; [11] stage1 sync; [12..13] claimed-role bitmap;
  // [16..143] sc0 test buffer (2 phases x 64).
  if (tid == 0) {
    unsigned xcc = ((unsigned)__builtin_amdgcn_s_getreg(XCC_GETREG_IMM)) & 7u;
    unsigned rank = atomicAdd(&cnt[xcc], 1u);
    int role = (xcc < 4u && rank < 16u) ? (int)(xcc * 16u + rank) : -1;
    if (role >= 0) atomicOr(&cnt[12 + (role >> 5)], 1u << (role & 31));
    asm volatile("s_waitcnt vmcnt(0)" ::: "memory");
    atomicAdd(&cnt[11], 1u);
    while (atomicAdd(&cnt[11], 0u) < (unsigned)SEQ_BLOCKS)
      __builtin_amdgcn_s_sleep(8);
    if (role < 0) {
      unsigned m0 = atomicAdd(&cnt[12], 0u);
      unsigned m1 = atomicAdd(&cnt[13], 0u);
      unsigned long long mask = ((unsigned long long)m1 << 32) | (unsigned long long)m0;
      unsigned long long inv = ~mask;           // zero bits = unclaimed roles
      unsigned nz = (unsigned)__builtin_popcountll(inv);
      unsigned gr = atomicAdd(&cnt[10], 1u);
      if (gr < nz) {
        unsigned long long v = inv;
        for (unsigned k = 0; k < gr; ++k) v &= v - 1;
        role = (int)__builtin_ctzll(v);
      }
    }
    s_role = role;
  }
  __syncthreads();
  const int role = s_role;
  if (role < 0) return;   // 192 spare blocks exit

  const int bg = role >> 4;   // batch group (16 batches)
  const int cg = role & 15;   // 32 c-indices per block
  const int lane = tid & 63;
  const int wv = tid >> 6;    // 8 waves
  const int grp = lane >> 4;  // k-group / m-subrange
  const int lr = lane & 15;
  const int g = lr >> 2;      // gate 0..3 (i,f,g,o)
  const int j = lr & 3;       // c sub-index
  const int cglob = cg * 32 + wv * 4 + j;
  const int nglob = g * CDIM + cglob;   // gate-matrix row

  // ---- bounded functional sc0 colocation test (8 ping-pong rounds) ----
  {
    unsigned* testb = cnt + 16;
    int ok = 1;
    for (int r = 0; r < 8; ++r) {
      if (tid == 0 && ok)
        st_sc0_u32(&testb[(r & 1) * 64 + role], 0xAB000000u | (unsigned)(r + 1));
      if (tid < 16 && ok) {
        const unsigned want = 0xAB000000u | (unsigned)(r + 1);
        int it = 0, done = 0;
        while (!done && it < 2500) {
          unsigned v = ld_sc0_u32(&testb[(r & 1) * 64 + bg * 16 + tid]);
          done = __all((int)(v == want));
          ++it;
        }
        if (!done) ok = 0;
      }
    }
    if (tid == 0) {
      atomicAdd(&cnt[8], ok ? 1u : 0u);
      asm volatile("s_waitcnt vmcnt(0)" ::: "memory");
      atomicAdd(&cnt[9], 1u);
      while (atomicAdd(&cnt[9], 0u) < 64u) __builtin_amdgcn_s_sleep(8);
      s_sc0 = (atomicAdd(&cnt[8], 0u) == 64u) ? 1 : 0;
    }
    __syncthreads();
  }
  const bool use_sc0 = (s_sc0 != 0);

  // ---- detect reset dtype (i32 / u8 / f32 / i64) ----
  __shared__ int s_oki, s_okf, s_oddnz;
  if (tid == 0) { s_oki = 1; s_okf = 1; s_oddnz = 0; }
  __syncthreads();
  {
    int oki = 1, okf = 1, oddnz = 0;
    for (int i = tid; i < 1024; i += SEQ_THREADS) {
      unsigned v = ((const unsigned*)rst)[i];
      oki &= (v <= 1u);
      okf &= (v == 0u || v == 0x3F800000u);
      if ((i & 1) && v != 0u) oddnz = 1;
    }
    if (!oki) atomicAnd(&s_oki, 0);
    if (!okf) atomicAnd(&s_okf, 0);
    if (oddnz) atomicOr(&s_oddnz, 1);
  }
  __syncthreads();
  const int mode = s_oki ? (s_oddnz ? 0 : 3) : (s_okf ? 2 : 1);

  // ---- build reset bitmask in LDS: RM[t] bit b = reset[t][b] ----
  for (int tt = wv; tt < TSTEPS; tt += 8) {
    int idx = tt * BATCH + lane;
    bool r;
    if (mode == 0)      r = ((const int*)rst)[idx] != 0;
    else if (mode == 1) r = ((const unsigned char*)rst)[idx] != 0;
    else if (mode == 2) r = ((const float*)rst)[idx] != 0.0f;
    else                r = ((const int*)rst)[2 * idx] != 0;
    unsigned long long bm = __ballot((int)r);
    if (lane == 0) RM[tt] = bm;
  }

  // ---- W_hh B-fragments into registers (16 cols per wave, permuted) ----
  short8 wfrag[16];
#pragma unroll
  for (int kk = 0; kk < 16; ++kk) {
    const float* s = whh + (size_t)nglob * CDIM + kk * 32 + grp * 8;
    float4 lo = *(const float4*)s, hi = *(const float4*)(s + 4);
    wfrag[kk] = pack8(lo, hi);
  }
  __syncthreads();  // RM ready

  // ---- xg for step 0 ----
  unsigned short xgc[4];
#pragma unroll
  for (int q = 0; q < 4; ++q)
    xgc[q] = xg[((size_t)(bg * 16 + grp * 4 + q)) * NGATE + nglob];

  float cReg[4] = {0.f, 0.f, 0.f, 0.f};

  // staging geometry: each wave stages 2 rows; 32 lanes per row
  const int srow = 2 * wv + (lane >> 5);
  const int wcol = lane & 31;

  for (int t = 0; t < TSTEPS; ++t) {
    const int pcur = t & 1, pnext = pcur ^ 1;
    char* habuf = smem + HA_OFF + pcur * 16384;

    // prefetch next step's xg slice early (HBM latency hides under poll)
    const int tn = (t + 1 < TSTEPS) ? t + 1 : t;
    unsigned short xgn[4];
#pragma unroll
    for (int q = 0; q < 4; ++q)
      xgn[q] = xg[((size_t)tn * BATCH + bg * 16 + grp * 4 + q) * NGATE + nglob];

    // ---- stage h[t-1] into LDS (self-certifying tagged words) ----
    if (t == 0) {
      float kp0 = ((RM[0] >> (bg * 16 + srow)) & 1ull) ? 0.f : 1.f;
#pragma unroll
      for (int i = 0; i < 2; ++i) {
        int p = wcol + 32 * i;          // 16B chunk 0..63
        const float* s = h0 + (size_t)(bg * 16 + srow) * CDIM + p * 8;
        float4 lo = *(const float4*)s, hi = *(const float4*)(s + 4);
        lo.x *= kp0; lo.y *= kp0; lo.z *= kp0; lo.w *= kp0;
        hi.x *= kp0; hi.y *= kp0; hi.z *= kp0; hi.w *= kp0;
        *(short8*)(habuf + srow * 1024 + ((p * 16) ^ ((srow & 7) << 4))) =
            pack8(lo, hi);
      }
    } else {
      const char* hqb = (const char*)hex +
          ((size_t)((pnext * 4 + bg) * 16 + srow) * 512 + (size_t)wcol * 2) * 4;
      const unsigned long long* hq = (const unsigned long long*)hqb;
      const unsigned tagexp = (unsigned)t;
      unsigned long long vals[8];
      if (use_sc0) {
        unsigned bad;
        do {
          ld8_sc0(hqb, vals[0], vals[1], vals[2], vals[3],
                  vals[4], vals[5], vals[6], vals[7]);
          bad = 0;
#pragma unroll
          for (int i = 0; i < 8; ++i)
            bad |= (((unsigned)vals[i] ^ tagexp) |
                    ((unsigned)(vals[i] >> 32) ^ tagexp)) & 0xffffu;
        } while (__any((int)bad));
      } else {
        unsigned pend = 0xffu;
        do {
#pragma unroll
          for (int i = 0; i < 8; ++i)
            if (pend & (1u << i))
              vals[i] = __hip_atomic_load(hq + 32 * i, __ATOMIC_RELAXED,
                                          __HIP_MEMORY_SCOPE_AGENT);
          unsigned np = 0;
#pragma unroll
          for (int i = 0; i < 8; ++i) {
            unsigned lo = (unsigned)vals[i];
            unsigned hi = (unsigned)(vals[i] >> 32);
            if (((lo & 0xffffu) != tagexp) || ((hi & 0xffffu) != tagexp))
              np |= 1u << i;
          }
          pend = np;
        } while (__any((int)pend));
      }
#pragma unroll
      for (int i = 0; i < 8; ++i) {
        int w = wcol + 32 * i;
        unsigned lo = (unsigned)vals[i];
        unsigned hi = (unsigned)(vals[i] >> 32);
        unsigned pk = (lo >> 16) | (hi & 0xffff0000u);
        *(unsigned*)(habuf + srow * 1024 + ((w * 4) ^ ((srow & 7) << 4))) = pk;
      }
    }
    __syncthreads();  // the ONLY barrier per step

    // ---- recurrent GEMM: 16x16 tile over K=512 ----
    f32x4 acc = {0.f, 0.f, 0.f, 0.f};
#pragma unroll
    for (int kk = 0; kk < 16; ++kk) {
      short8 a = *(const short8*)(habuf + lr * 1024 +
                                  ((kk * 64 + grp * 16) ^ ((lr & 7) << 4)));
      acc = __builtin_amdgcn_mfma_f32_16x16x32_bf16(a, wfrag[kk], acc, 0, 0, 0);
    }

    // ---- in-register cell: butterfly transpose of gate quadrants ----
    const unsigned long long kw = RM[t];
    const unsigned long long kw1 = RM[tn];
    float hsel = 0.f;
#pragma unroll
    for (int q = 0; q < 4; ++q) {
      float v0f = acc[q] + bf2f(xgc[q]);
      float ex1 = __shfl_xor(v0f, 4);
      float a = (g & 1) ? ex1 : v0f;
      float b = (g & 1) ? v0f : ex1;
      float exA = __shfl_xor(a, 8);
      float exB = __shfl_xor(b, 8);
      float gi = (g & 2) ? exA : a;
      float gf = (g & 2) ? exB : b;
      float gg = (g & 2) ? a : exA;
      float go = (g & 2) ? b : exB;
      int m = grp * 4 + q;
      float kp = ((kw >> (bg * 16 + m)) & 1ull) ? 0.f : 1.f;
      float cprev = (t == 0) ? c0[(size_t)(bg * 16 + m) * CDIM + cglob] : cReg[q];
      cprev *= kp;
      float cn = sigm(gf) * cprev + sigm(gi) * tanhf(gg);
      cReg[q] = cn;
      if (q == g) hsel = sigm(go) * tanhf(cn);
    }

    // ---- fire-and-forget tagged h store (pre-masked with reset[t+1]) ----
    const int msel = grp * 4 + g;
    if (t + 1 < TSTEPS) {
      bool r1 = (kw1 >> (bg * 16 + msel)) & 1ull;
      unsigned short hb = r1 ? (unsigned short)0 : f2bf(hsel);
      unsigned word = ((unsigned)hb << 16) | (unsigned)(t + 1);
      unsigned* hp = hex + (size_t)((pcur * 4 + bg) * 16 + msel) * 512 + cglob;
      if (use_sc0) st_sc0_u32(hp, word);
      else __hip_atomic_store(hp, word, __ATOMIC_RELAXED, __HIP_MEMORY_SCOPE_AGENT);
    }

    // y store off the critical path
    y[((size_t)t * BATCH + bg * 16 + msel) * CDIM + cglob] = hsel;

#pragma unroll
    for (int q = 0; q < 4; ++q) xgc[q] = xgn[q];
  }
}

extern "C" void kernel_launch(void* const* d_in, const int* in_sizes, int n_in,
                              void* d_out, int out_size, void* d_ws, size_t ws_size,
                              hipStream_t stream) {
  (void)in_sizes; (void)n_in; (void)out_size;
  const float* x = (const float*)d_in[0];
  const void* rstp = (const void*)d_in[1];
  const float* h0 = (const float*)d_in[2];
  const float* c0 = (const float*)d_in[3];
  const float* wih = (const float*)d_in[4];
  const float* whh = (const float*)d_in[5];
  const float* bih = (const float*)d_in[6];
  const float* bhh = (const float*)d_in[7];
  float* y = (float*)d_out;

  if (ws_size < WS_NEED) return;  // diagnosable clean failure

  unsigned short* xgp = (unsigned short*)d_ws;
  unsigned* hex = (unsigned*)((char*)d_ws + HEX_OFF);
  unsigned* cnt = (unsigned*)((char*)d_ws + CNT_OFF);

  // clear tags + election/consensus/test region every call (graph-safe)
  (void)hipMemsetAsync((char*)d_ws + HEX_OFF, 0, HEX_BYTES + 1024, stream);

  // pre-pass: xg = x @ W_ih^T + bih + bhh   (8192 blocks: 512 bm x 16 bn)
  xg_prepass<<<dim3(8192), dim3(256), 0, stream>>>(x, wih, bih, bhh, xgp);

  (void)hipFuncSetAttribute(reinterpret_cast<const void*>(rlstm_seq),
                            hipFuncAttributeMaxDynamicSharedMemorySize, SMEM_BYTES);
  void* args[] = {(void*)&rstp, (void*)&h0, (void*)&c0, (void*)&whh,
                  (void*)&y,    (void*)&xgp, (void*)&hex, (void*)&cnt};
  (void)hipLaunchCooperativeKernel((void*)rlstm_seq, dim3(SEQ_BLOCKS),
                                   dim3(SEQ_THREADS), args, SMEM_BYTES, stream);
}

// Round 8
// 4975.315 us; speedup vs baseline: 1.8058x; 1.8058x over previous
//
#include <hip/hip_runtime.h>
#include <math.h>

typedef __attribute__((ext_vector_type(8))) short short8;
typedef __attribute__((ext_vector_type(4))) float f32x4;

#define TSTEPS 1024
#define BATCH  64
#define CDIM   512
#define NGATE  2048

// ---- workspace layout ----
#define XG_BYTES ((size_t)TSTEPS * BATCH * NGATE * 2)   // 256 MiB bf16
#define HEX_OFF  XG_BYTES
// hex: u32 [phase][bg][row][c] tagged words = 2*4*16*512*4 = 256 KiB
#define HEX_BYTES (2 * 4 * 16 * 512 * 4)
#define WS_NEED  (HEX_OFF + HEX_BYTES)

// ---- sequential kernel geometry: 64 blocks (4 bg x 16 cg) x 512 thr ----
#define SEQ_BLOCKS  64
#define SEQ_THREADS 512
#define SMEM_BYTES  98304   // pad to force 1 block/CU -> full VGPR budget
#define HA_OFF  0           // 2 x (16 x 512 bf16 swizzled) = 32768 (double buffer)
#define RM_OFF  32768       // 1024 u64 reset bitmask = 8192
#define HST_OFF 40960       // h store staging: 16 rows x 32 u32 = 2048 B

__device__ __forceinline__ unsigned short f2bf(float x) {
  unsigned u = __builtin_bit_cast(unsigned, x);
  unsigned r = (u + 0x7FFFu + ((u >> 16) & 1u)) >> 16;
  return (unsigned short)r;
}
__device__ __forceinline__ float bf2f(unsigned short b) {
  unsigned u = ((unsigned)b) << 16;
  return __builtin_bit_cast(float, u);
}
__device__ __forceinline__ short8 pack8(float4 lo, float4 hi) {
  short8 r;
  r[0] = (short)f2bf(lo.x); r[1] = (short)f2bf(lo.y);
  r[2] = (short)f2bf(lo.z); r[3] = (short)f2bf(lo.w);
  r[4] = (short)f2bf(hi.x); r[5] = (short)f2bf(hi.y);
  r[6] = (short)f2bf(hi.z); r[7] = (short)f2bf(hi.w);
  return r;
}
__device__ __forceinline__ float sigm(float z) { return 1.0f / (1.0f + expf(-z)); }

// ============ kernel 1: xg[t,b,n] = x[t,b,:]@W_ih[n,:] + bih[n]+bhh[n] ======
__global__ __launch_bounds__(256, 2) void xg_prepass(
    const float* __restrict__ x, const float* __restrict__ wih,
    const float* __restrict__ bih, const float* __restrict__ bhh,
    unsigned short* __restrict__ xg) {
  __shared__ __align__(16) char lds[32768];
  char* Al = lds;
  char* Bl = lds + 16384;
  const int tid = threadIdx.x;
  const int bid = blockIdx.x;
  const int bm = bid & 511, bn = bid >> 9;
  const int lane = tid & 63, wv = tid >> 6;
  const int wm = wv >> 1, wn = wv & 1;
  const int grp = lane >> 4, lr = lane & 15;

  f32x4 acc[4][4] = {};
  float bsum[4];
#pragma unroll
  for (int nt = 0; nt < 4; ++nt) {
    int n = bn * 128 + wn * 64 + nt * 16 + lr;
    bsum[nt] = bih[n] + bhh[n];
  }

  for (int kb = 0; kb < 8; ++kb) {
    __syncthreads();
#pragma unroll
    for (int c = 0; c < 4; ++c) {
      int gi = tid + c * 256;
      int row = gi >> 3, colc = (gi & 7) * 8;
      const float* sA = x + ((size_t)(bm * 128 + row)) * 512 + kb * 64 + colc;
      float4 lo = *(const float4*)sA, hi = *(const float4*)(sA + 4);
      *(short8*)(Al + row * 128 + ((colc * 2) ^ ((row & 7) << 4))) = pack8(lo, hi);
      const float* sB = wih + ((size_t)(bn * 128 + row)) * 512 + kb * 64 + colc;
      float4 lo2 = *(const float4*)sB, hi2 = *(const float4*)(sB + 4);
      *(short8*)(Bl + row * 128 + ((colc * 2) ^ ((row & 7) << 4))) = pack8(lo2, hi2);
    }
    __syncthreads();
#pragma unroll
    for (int kk = 0; kk < 2; ++kk) {
      short8 af[4], bf[4];
#pragma unroll
      for (int mt = 0; mt < 4; ++mt) {
        int r = wm * 64 + mt * 16 + lr;
        af[mt] = *(const short8*)(Al + r * 128 + ((kk * 64 + grp * 16) ^ ((r & 7) << 4)));
      }
#pragma unroll
      for (int nt = 0; nt < 4; ++nt) {
        int r = wn * 64 + nt * 16 + lr;
        bf[nt] = *(const short8*)(Bl + r * 128 + ((kk * 64 + grp * 16) ^ ((r & 7) << 4)));
      }
#pragma unroll
      for (int mt = 0; mt < 4; ++mt)
#pragma unroll
        for (int nt = 0; nt < 4; ++nt)
          acc[mt][nt] = __builtin_amdgcn_mfma_f32_16x16x32_bf16(af[mt], bf[nt],
                                                                acc[mt][nt], 0, 0, 0);
    }
  }
#pragma unroll
  for (int mt = 0; mt < 4; ++mt)
#pragma unroll
    for (int nt = 0; nt < 4; ++nt)
#pragma unroll
      for (int q = 0; q < 4; ++q) {
        int m = bm * 128 + wm * 64 + mt * 16 + grp * 4 + q;
        int n = bn * 128 + wn * 64 + nt * 16 + lr;
        xg[(size_t)m * NGATE + n] = f2bf(acc[mt][nt][q] + bsum[nt]);
      }
}

// ============ kernel 2: persistent sequential LSTM ==========================
// h exchange word: (h_bf16 << 16) | step_tag. Tag match => payload valid.
// Producer side: LDS repack + single-wave coalesced u64 agent stores.
__global__ __launch_bounds__(SEQ_THREADS, 1) void rlstm_seq(
    const void* __restrict__ rst, const float* __restrict__ h0,
    const float* __restrict__ c0, const float* __restrict__ whh,
    float* __restrict__ y, const unsigned short* __restrict__ xg,
    unsigned* __restrict__ hex) {
  extern __shared__ __align__(16) char smem[];
  unsigned long long* RM = (unsigned long long*)(smem + RM_OFF);
  unsigned* HST32 = (unsigned*)(smem + HST_OFF);
  unsigned long long* HST64 = (unsigned long long*)(smem + HST_OFF);

  const int tid = threadIdx.x;
  const int bid = blockIdx.x;
  const int bg = bid >> 4;    // batch group (16 batches)
  const int cg = bid & 15;    // 32 c-indices per block
  const int lane = tid & 63;
  const int wv = tid >> 6;    // 8 waves
  const int grp = lane >> 4;  // k-group / m-subrange
  const int lr = lane & 15;
  const int g = lr >> 2;      // gate 0..3 (i,f,g,o)
  const int j = lr & 3;       // c sub-index
  const int lcol = wv * 4 + j;            // block-local c 0..31
  const int cglob = cg * 32 + lcol;
  const int nglob = g * CDIM + cglob;     // gate-matrix row

  // ---- detect reset dtype (i32 / u8 / f32 / i64) ----
  __shared__ int s_oki, s_okf, s_oddnz;
  if (tid == 0) { s_oki = 1; s_okf = 1; s_oddnz = 0; }
  __syncthreads();
  {
    int oki = 1, okf = 1, oddnz = 0;
    for (int i = tid; i < 1024; i += SEQ_THREADS) {
      unsigned v = ((const unsigned*)rst)[i];
      oki &= (v <= 1u);
      okf &= (v == 0u || v == 0x3F800000u);
      if ((i & 1) && v != 0u) oddnz = 1;
    }
    if (!oki) atomicAnd(&s_oki, 0);
    if (!okf) atomicAnd(&s_okf, 0);
    if (oddnz) atomicOr(&s_oddnz, 1);
  }
  __syncthreads();
  const int mode = s_oki ? (s_oddnz ? 0 : 3) : (s_okf ? 2 : 1);

  // ---- build reset bitmask in LDS: RM[t] bit b = reset[t][b] ----
  for (int tt = wv; tt < TSTEPS; tt += 8) {
    int idx = tt * BATCH + lane;
    bool r;
    if (mode == 0)      r = ((const int*)rst)[idx] != 0;
    else if (mode == 1) r = ((const unsigned char*)rst)[idx] != 0;
    else if (mode == 2) r = ((const float*)rst)[idx] != 0.0f;
    else                r = ((const int*)rst)[2 * idx] != 0;
    unsigned long long bm = __ballot((int)r);
    if (lane == 0) RM[tt] = bm;
  }

  // ---- W_hh B-fragments into registers (16 cols per wave, permuted) ----
  short8 wfrag[16];
#pragma unroll
  for (int kk = 0; kk < 16; ++kk) {
    const float* s = whh + (size_t)nglob * CDIM + kk * 32 + grp * 8;
    float4 lo = *(const float4*)s, hi = *(const float4*)(s + 4);
    wfrag[kk] = pack8(lo, hi);
  }
  __syncthreads();  // RM ready

  // ---- xg for step 0 ----
  unsigned short xgc[4];
#pragma unroll
  for (int q = 0; q < 4; ++q)
    xgc[q] = xg[((size_t)(bg * 16 + grp * 4 + q)) * NGATE + nglob];

  float cReg[4] = {0.f, 0.f, 0.f, 0.f};

  // staging geometry: each wave stages 2 rows; 32 lanes per row
  const int srow = 2 * wv + (lane >> 5);
  const int wcol = lane & 31;

  for (int t = 0; t < TSTEPS; ++t) {
    const int pcur = t & 1, pnext = pcur ^ 1;
    char* habuf = smem + HA_OFF + pcur * 16384;

    // prefetch next step's xg slice early (HBM latency hides under poll)
    const int tn = (t + 1 < TSTEPS) ? t + 1 : t;
    unsigned short xgn[4];
#pragma unroll
    for (int q = 0; q < 4; ++q)
      xgn[q] = xg[((size_t)tn * BATCH + bg * 16 + grp * 4 + q) * NGATE + nglob];

    // ---- stage h[t-1] into LDS (self-certifying tagged words) ----
    if (t == 0) {
      float kp0 = ((RM[0] >> (bg * 16 + srow)) & 1ull) ? 0.f : 1.f;
#pragma unroll
      for (int i = 0; i < 2; ++i) {
        int p = wcol + 32 * i;          // 16B chunk 0..63
        const float* s = h0 + (size_t)(bg * 16 + srow) * CDIM + p * 8;
        float4 lo = *(const float4*)s, hi = *(const float4*)(s + 4);
        lo.x *= kp0; lo.y *= kp0; lo.z *= kp0; lo.w *= kp0;
        hi.x *= kp0; hi.y *= kp0; hi.z *= kp0; hi.w *= kp0;
        *(short8*)(habuf + srow * 1024 + ((p * 16) ^ ((srow & 7) << 4))) =
            pack8(lo, hi);
      }
    } else {
      const unsigned long long* hq = (const unsigned long long*)hex +
          (size_t)((pnext * 4 + bg) * 16 + srow) * 256 + wcol;
      const unsigned tagexp = (unsigned)t;
      unsigned long long vals[8];
      unsigned pend = 0xffu;
      int round = 0;
      do {
        if (round++) __builtin_amdgcn_s_sleep(1);  // back off: let stores drain
#pragma unroll
        for (int i = 0; i < 8; ++i)
          if (pend & (1u << i))
            vals[i] = __hip_atomic_load(hq + 32 * i, __ATOMIC_RELAXED,
                                        __HIP_MEMORY_SCOPE_AGENT);
        unsigned np = 0;
#pragma unroll
        for (int i = 0; i < 8; ++i) {
          unsigned lo = (unsigned)vals[i];
          unsigned hi = (unsigned)(vals[i] >> 32);
          if (((lo & 0xffffu) != tagexp) || ((hi & 0xffffu) != tagexp))
            np |= 1u << i;
        }
        pend = np;
      } while (__any((int)pend));
#pragma unroll
      for (int i = 0; i < 8; ++i) {
        int w = wcol + 32 * i;
        unsigned lo = (unsigned)vals[i];
        unsigned hi = (unsigned)(vals[i] >> 32);
        unsigned pk = (lo >> 16) | (hi & 0xffff0000u);
        *(unsigned*)(habuf + srow * 1024 + ((w * 4) ^ ((srow & 7) << 4))) = pk;
      }
    }
    __syncthreads();  // B1: hA ready

    // ---- recurrent GEMM: 16x16 tile over K=512 ----
    f32x4 acc = {0.f, 0.f, 0.f, 0.f};
#pragma unroll
    for (int kk = 0; kk < 16; ++kk) {
      short8 a = *(const short8*)(habuf + lr * 1024 +
                                  ((kk * 64 + grp * 16) ^ ((lr & 7) << 4)));
      acc = __builtin_amdgcn_mfma_f32_16x16x32_bf16(a, wfrag[kk], acc, 0, 0, 0);
    }

    // ---- in-register cell: butterfly transpose of gate quadrants ----
    const unsigned long long kw = RM[t];
    const unsigned long long kw1 = RM[tn];
    float hsel = 0.f;
#pragma unroll
    for (int q = 0; q < 4; ++q) {
      float v0f = acc[q] + bf2f(xgc[q]);
      float ex1 = __shfl_xor(v0f, 4);
      float a = (g & 1) ? ex1 : v0f;
      float b = (g & 1) ? v0f : ex1;
      float exA = __shfl_xor(a, 8);
      float exB = __shfl_xor(b, 8);
      float gi = (g & 2) ? exA : a;
      float gf = (g & 2) ? exB : b;
      float gg = (g & 2) ? a : exA;
      float go = (g & 2) ? b : exB;
      int m = grp * 4 + q;
      float kp = ((kw >> (bg * 16 + m)) & 1ull) ? 0.f : 1.f;
      float cprev = (t == 0) ? c0[(size_t)(bg * 16 + m) * CDIM + cglob] : cReg[q];
      cprev *= kp;
      float cn = sigm(gf) * cprev + sigm(gi) * tanhf(gg);
      cReg[q] = cn;
      if (q == g) hsel = sigm(go) * tanhf(cn);
    }

    // ---- repack tagged h words in LDS, then coalesced u64 agent stores ----
    const int msel = grp * 4 + g;
    {
      bool r1 = (kw1 >> (bg * 16 + msel)) & 1ull;
      unsigned short hb = r1 ? (unsigned short)0 : f2bf(hsel);
      HST32[msel * 32 + lcol] = ((unsigned)hb << 16) | (unsigned)(t + 1);
    }
    __syncthreads();  // B2: HST complete
    if (wv == 0 && t + 1 < TSTEPS) {
      unsigned long long* hqd = (unsigned long long*)hex;
#pragma unroll
      for (int i = 0; i < 4; ++i) {
        int chunk = i * 64 + lane;        // 0..255 (u64 units), lane-major
        int row = chunk >> 4, cp = chunk & 15;
        unsigned long long v = HST64[chunk];
        __hip_atomic_store(hqd + (size_t)((pcur * 4 + bg) * 16 + row) * 256 +
                               cg * 16 + cp,
                           v, __ATOMIC_RELAXED, __HIP_MEMORY_SCOPE_AGENT);
      }
    }

    // y store off the critical path
    y[((size_t)t * BATCH + bg * 16 + msel) * CDIM + cglob] = hsel;

#pragma unroll
    for (int q = 0; q < 4; ++q) xgc[q] = xgn[q];
  }
}

extern "C" void kernel_launch(void* const* d_in, const int* in_sizes, int n_in,
                              void* d_out, int out_size, void* d_ws, size_t ws_size,
                              hipStream_t stream) {
  (void)in_sizes; (void)n_in; (void)out_size;
  const float* x = (const float*)d_in[0];
  const void* rstp = (const void*)d_in[1];
  const float* h0 = (const float*)d_in[2];
  const float* c0 = (const float*)d_in[3];
  const float* wih = (const float*)d_in[4];
  const float* whh = (const float*)d_in[5];
  const float* bih = (const float*)d_in[6];
  const float* bhh = (const float*)d_in[7];
  float* y = (float*)d_out;

  if (ws_size < WS_NEED) return;  // diagnosable clean failure

  unsigned short* xgp = (unsigned short*)d_ws;
  unsigned* hex = (unsigned*)((char*)d_ws + HEX_OFF);

  // clear tags (stale tags from a previous replay would alias at t=1023)
  (void)hipMemsetAsync((char*)d_ws + HEX_OFF, 0, HEX_BYTES, stream);

  // pre-pass: xg = x @ W_ih^T + bih + bhh   (8192 blocks: 512 bm x 16 bn)
  xg_prepass<<<dim3(8192), dim3(256), 0, stream>>>(x, wih, bih, bhh, xgp);

  (void)hipFuncSetAttribute(reinterpret_cast<const void*>(rlstm_seq),
                            hipFuncAttributeMaxDynamicSharedMemorySize, SMEM_BYTES);
  void* args[] = {(void*)&rstp, (void*)&h0, (void*)&c0, (void*)&whh,
                  (void*)&y,    (void*)&xgp, (void*)&hex};
  (void)hipLaunchCooperativeKernel((void*)rlstm_seq, dim3(SEQ_BLOCKS),
                                   dim3(SEQ_THREADS), args, SMEM_BYTES, stream);
}

// Round 9
// 4813.961 us; speedup vs baseline: 1.8663x; 1.0335x over previous
//
#include <hip/hip_runtime.h>
#include <math.h>

typedef __attribute__((ext_vector_type(8))) short short8;
typedef __attribute__((ext_vector_type(4))) float f32x4;

#define TSTEPS 1024
#define BATCH  64
#define CDIM   512
#define NGATE  2048

// ---- workspace layout ----
#define XG_BYTES ((size_t)TSTEPS * BATCH * NGATE * 2)   // 256 MiB bf16
#define HEX_OFF  XG_BYTES
// hex data: bf16 [phase][bg][row][c] = 2*4*16*512*2 = 128 KiB (no tags)
#define HEX_BYTES (2 * 4 * 16 * 512 * 2)
// flags: u32 [bg][cg], spread 16 words (64 B) apart = 4 KiB, monotone step count
#define FLG_OFF  (HEX_OFF + HEX_BYTES)
#define FLG_BYTES (64 * 16 * 4)
#define WS_NEED  (FLG_OFF + FLG_BYTES)

// ---- sequential kernel geometry: 64 blocks (4 bg x 16 cg) x 512 thr ----
#define SEQ_BLOCKS  64
#define SEQ_THREADS 512
#define SMEM_BYTES  98304   // pad to force 1 block/CU -> full VGPR budget
#define HA_OFF  0           // 2 x (16 x 512 bf16 swizzled) = 32768 (double buffer)
#define RM_OFF  32768       // 1024 u64 reset bitmask = 8192
#define HST_OFF 40960       // h store staging: 16 rows x 32 bf16 = 1024 B

__device__ __forceinline__ unsigned short f2bf(float x) {
  unsigned u = __builtin_bit_cast(unsigned, x);
  unsigned r = (u + 0x7FFFu + ((u >> 16) & 1u)) >> 16;
  return (unsigned short)r;
}
__device__ __forceinline__ float bf2f(unsigned short b) {
  unsigned u = ((unsigned)b) << 16;
  return __builtin_bit_cast(float, u);
}
__device__ __forceinline__ short8 pack8(float4 lo, float4 hi) {
  short8 r;
  r[0] = (short)f2bf(lo.x); r[1] = (short)f2bf(lo.y);
  r[2] = (short)f2bf(lo.z); r[3] = (short)f2bf(lo.w);
  r[4] = (short)f2bf(hi.x); r[5] = (short)f2bf(hi.y);
  r[6] = (short)f2bf(hi.z); r[7] = (short)f2bf(hi.w);
  return r;
}
// fast, NaN-safe at extremes: 1/(1+e^-z); e^inf -> inf -> 0 is IEEE-correct
__device__ __forceinline__ float sigm(float z) { return 1.0f / (1.0f + __expf(-z)); }
// tanh(x) = 2/(1+e^(-2x)) - 1 : saturates to +/-1 without inf/inf NaN
__device__ __forceinline__ float tanh_f(float x) {
  return 2.0f / (1.0f + __expf(-2.0f * x)) - 1.0f;
}

// ============ kernel 1: xg[t,b,n] = x[t,b,:]@W_ih[n,:] + bih[n]+bhh[n] ======
__global__ __launch_bounds__(256, 2) void xg_prepass(
    const float* __restrict__ x, const float* __restrict__ wih,
    const float* __restrict__ bih, const float* __restrict__ bhh,
    unsigned short* __restrict__ xg) {
  __shared__ __align__(16) char lds[32768];
  char* Al = lds;
  char* Bl = lds + 16384;
  const int tid = threadIdx.x;
  const int bid = blockIdx.x;
  const int bm = bid & 511, bn = bid >> 9;
  const int lane = tid & 63, wv = tid >> 6;
  const int wm = wv >> 1, wn = wv & 1;
  const int grp = lane >> 4, lr = lane & 15;

  f32x4 acc[4][4] = {};
  float bsum[4];
#pragma unroll
  for (int nt = 0; nt < 4; ++nt) {
    int n = bn * 128 + wn * 64 + nt * 16 + lr;
    bsum[nt] = bih[n] + bhh[n];
  }

  for (int kb = 0; kb < 8; ++kb) {
    __syncthreads();
#pragma unroll
    for (int c = 0; c < 4; ++c) {
      int gi = tid + c * 256;
      int row = gi >> 3, colc = (gi & 7) * 8;
      const float* sA = x + ((size_t)(bm * 128 + row)) * 512 + kb * 64 + colc;
      float4 lo = *(const float4*)sA, hi = *(const float4*)(sA + 4);
      *(short8*)(Al + row * 128 + ((colc * 2) ^ ((row & 7) << 4))) = pack8(lo, hi);
      const float* sB = wih + ((size_t)(bn * 128 + row)) * 512 + kb * 64 + colc;
      float4 lo2 = *(const float4*)sB, hi2 = *(const float4*)(sB + 4);
      *(short8*)(Bl + row * 128 + ((colc * 2) ^ ((row & 7) << 4))) = pack8(lo2, hi2);
    }
    __syncthreads();
#pragma unroll
    for (int kk = 0; kk < 2; ++kk) {
      short8 af[4], bf[4];
#pragma unroll
      for (int mt = 0; mt < 4; ++mt) {
        int r = wm * 64 + mt * 16 + lr;
        af[mt] = *(const short8*)(Al + r * 128 + ((kk * 64 + grp * 16) ^ ((r & 7) << 4)));
      }
#pragma unroll
      for (int nt = 0; nt < 4; ++nt) {
        int r = wn * 64 + nt * 16 + lr;
        bf[nt] = *(const short8*)(Bl + r * 128 + ((kk * 64 + grp * 16) ^ ((r & 7) << 4)));
      }
#pragma unroll
      for (int mt = 0; mt < 4; ++mt)
#pragma unroll
        for (int nt = 0; nt < 4; ++nt)
          acc[mt][nt] = __builtin_amdgcn_mfma_f32_16x16x32_bf16(af[mt], bf[nt],
                                                                acc[mt][nt], 0, 0, 0);
    }
  }
#pragma unroll
  for (int mt = 0; mt < 4; ++mt)
#pragma unroll
    for (int nt = 0; nt < 4; ++nt)
#pragma unroll
      for (int q = 0; q < 4; ++q) {
        int m = bm * 128 + wm * 64 + mt * 16 + grp * 4 + q;
        int n = bn * 128 + wn * 64 + nt * 16 + lr;
        xg[(size_t)m * NGATE + n] = f2bf(acc[mt][nt][q] + bsum[nt]);
      }
}

// ============ kernel 2: persistent sequential LSTM ==========================
// Exchange: bf16 h data (plain payload) + per-block monotone step flag.
// Producer: LDS repack -> wave0 coalesced u64 agent stores -> vmcnt(0) -> flag.
// Consumer: poll 16 tiny flags, then one bulk tag-free data load.
__global__ __launch_bounds__(SEQ_THREADS, 1) void rlstm_seq(
    const void* __restrict__ rst, const float* __restrict__ h0,
    const float* __restrict__ c0, const float* __restrict__ whh,
    float* __restrict__ y, const unsigned short* __restrict__ xg,
    unsigned short* __restrict__ hexd, unsigned* __restrict__ flg) {
  extern __shared__ __align__(16) char smem[];
  unsigned long long* RM = (unsigned long long*)(smem + RM_OFF);
  unsigned short* HST16 = (unsigned short*)(smem + HST_OFF);
  unsigned long long* HST64 = (unsigned long long*)(smem + HST_OFF);

  const int tid = threadIdx.x;
  const int bid = blockIdx.x;
  const int bg = bid >> 4;    // batch group (16 batches)
  const int cg = bid & 15;    // 32 c-indices per block
  const int lane = tid & 63;
  const int wv = tid >> 6;    // 8 waves
  const int grp = lane >> 4;  // k-group / m-subrange
  const int lr = lane & 15;
  const int g = lr >> 2;      // gate 0..3 (i,f,g,o)
  const int j = lr & 3;       // c sub-index
  const int lcol = wv * 4 + j;            // block-local c 0..31
  const int cglob = cg * 32 + lcol;
  const int nglob = g * CDIM + cglob;     // gate-matrix row

  // ---- detect reset dtype (i32 / u8 / f32 / i64) ----
  __shared__ int s_oki, s_okf, s_oddnz;
  if (tid == 0) { s_oki = 1; s_okf = 1; s_oddnz = 0; }
  __syncthreads();
  {
    int oki = 1, okf = 1, oddnz = 0;
    for (int i = tid; i < 1024; i += SEQ_THREADS) {
      unsigned v = ((const unsigned*)rst)[i];
      oki &= (v <= 1u);
      okf &= (v == 0u || v == 0x3F800000u);
      if ((i & 1) && v != 0u) oddnz = 1;
    }
    if (!oki) atomicAnd(&s_oki, 0);
    if (!okf) atomicAnd(&s_okf, 0);
    if (oddnz) atomicOr(&s_oddnz, 1);
  }
  __syncthreads();
  const int mode = s_oki ? (s_oddnz ? 0 : 3) : (s_okf ? 2 : 1);

  // ---- build reset bitmask in LDS: RM[t] bit b = reset[t][b] ----
  for (int tt = wv; tt < TSTEPS; tt += 8) {
    int idx = tt * BATCH + lane;
    bool r;
    if (mode == 0)      r = ((const int*)rst)[idx] != 0;
    else if (mode == 1) r = ((const unsigned char*)rst)[idx] != 0;
    else if (mode == 2) r = ((const float*)rst)[idx] != 0.0f;
    else                r = ((const int*)rst)[2 * idx] != 0;
    unsigned long long bm = __ballot((int)r);
    if (lane == 0) RM[tt] = bm;
  }

  // ---- W_hh B-fragments into registers (16 cols per wave, permuted) ----
  short8 wfrag[16];
#pragma unroll
  for (int kk = 0; kk < 16; ++kk) {
    const float* s = whh + (size_t)nglob * CDIM + kk * 32 + grp * 8;
    float4 lo = *(const float4*)s, hi = *(const float4*)(s + 4);
    wfrag[kk] = pack8(lo, hi);
  }
  __syncthreads();  // RM ready

  // ---- xg for step 0 ----
  unsigned short xgc[4];
#pragma unroll
  for (int q = 0; q < 4; ++q)
    xgc[q] = xg[((size_t)(bg * 16 + grp * 4 + q)) * NGATE + nglob];

  float cReg[4] = {0.f, 0.f, 0.f, 0.f};

  // staging geometry: each wave stages 2 rows; 32 lanes per row
  const int srow = 2 * wv + (lane >> 5);
  const int wcol = lane & 31;

  for (int t = 0; t < TSTEPS; ++t) {
    const int pcur = t & 1, pnext = pcur ^ 1;
    char* habuf = smem + HA_OFF + pcur * 16384;

    // prefetch next step's xg slice early (HBM latency hides under poll)
    const int tn = (t + 1 < TSTEPS) ? t + 1 : t;
    unsigned short xgn[4];
#pragma unroll
    for (int q = 0; q < 4; ++q)
      xgn[q] = xg[((size_t)tn * BATCH + bg * 16 + grp * 4 + q) * NGATE + nglob];

    // ---- acquire h[t-1] and stage into LDS ----
    if (t == 0) {
      float kp0 = ((RM[0] >> (bg * 16 + srow)) & 1ull) ? 0.f : 1.f;
#pragma unroll
      for (int i = 0; i < 2; ++i) {
        int p = wcol + 32 * i;          // 16B chunk 0..63
        const float* s = h0 + (size_t)(bg * 16 + srow) * CDIM + p * 8;
        float4 lo = *(const float4*)s, hi = *(const float4*)(s + 4);
        lo.x *= kp0; lo.y *= kp0; lo.z *= kp0; lo.w *= kp0;
        hi.x *= kp0; hi.y *= kp0; hi.z *= kp0; hi.w *= kp0;
        *(short8*)(habuf + srow * 1024 + ((p * 16) ^ ((srow & 7) << 4))) =
            pack8(lo, hi);
      }
    } else {
      // poll the 16 producer flags of this bg (tiny traffic)
      {
        const unsigned tgt = (unsigned)t;
        int round = 0;
        while (true) {
          unsigned v = __hip_atomic_load(&flg[(bg * 16 + (lane & 15)) * 16],
                                         __ATOMIC_RELAXED, __HIP_MEMORY_SCOPE_AGENT);
          if (__all((int)(v >= tgt))) break;
          if (round++) __builtin_amdgcn_s_sleep(1);
        }
        asm volatile("" ::: "memory");
      }
      // bulk tag-free data load: 4 u64 per lane, coalesced
      const unsigned long long* hq = (const unsigned long long*)hexd +
          (size_t)((pnext * 4 + bg) * 16 + srow) * 128;
      unsigned long long vals[4];
#pragma unroll
      for (int i = 0; i < 4; ++i)
        vals[i] = __hip_atomic_load(hq + wcol + 32 * i, __ATOMIC_RELAXED,
                                    __HIP_MEMORY_SCOPE_AGENT);
#pragma unroll
      for (int i = 0; i < 4; ++i) {
        int col = wcol + 32 * i;        // u64 index within row (8B units)
        *(unsigned long long*)(habuf + srow * 1024 +
                               ((col * 8) ^ ((srow & 7) << 4))) = vals[i];
      }
    }
    __syncthreads();  // B1: hA ready

    // ---- recurrent GEMM: 16x16 tile over K=512, dual dependency chains ----
    f32x4 acc0 = {0.f, 0.f, 0.f, 0.f}, acc1 = {0.f, 0.f, 0.f, 0.f};
#pragma unroll
    for (int kk = 0; kk < 16; ++kk) {
      short8 a = *(const short8*)(habuf + lr * 1024 +
                                  ((kk * 64 + grp * 16) ^ ((lr & 7) << 4)));
      if (kk & 1)
        acc1 = __builtin_amdgcn_mfma_f32_16x16x32_bf16(a, wfrag[kk], acc1, 0, 0, 0);
      else
        acc0 = __builtin_amdgcn_mfma_f32_16x16x32_bf16(a, wfrag[kk], acc0, 0, 0, 0);
    }
    f32x4 acc = acc0 + acc1;

    // ---- in-register cell: butterfly transpose of gate quadrants ----
    const unsigned long long kw = RM[t];
    const unsigned long long kw1 = RM[tn];
    float hsel = 0.f;
#pragma unroll
    for (int q = 0; q < 4; ++q) {
      float v0f = acc[q] + bf2f(xgc[q]);
      float ex1 = __shfl_xor(v0f, 4);
      float a = (g & 1) ? ex1 : v0f;
      float b = (g & 1) ? v0f : ex1;
      float exA = __shfl_xor(a, 8);
      float exB = __shfl_xor(b, 8);
      float gi = (g & 2) ? exA : a;
      float gf = (g & 2) ? exB : b;
      float gg = (g & 2) ? a : exA;
      float go = (g & 2) ? b : exB;
      int m = grp * 4 + q;
      float kp = ((kw >> (bg * 16 + m)) & 1ull) ? 0.f : 1.f;
      float cprev = (t == 0) ? c0[(size_t)(bg * 16 + m) * CDIM + cglob] : cReg[q];
      cprev *= kp;
      float cn = sigm(gf) * cprev + sigm(gi) * tanh_f(gg);
      cReg[q] = cn;
      if (q == g) hsel = sigm(go) * tanh_f(cn);
    }

    // ---- repack bf16 h in LDS, wave0 coalesced stores, vmcnt, flag ----
    const int msel = grp * 4 + g;
    {
      bool r1 = (kw1 >> (bg * 16 + msel)) & 1ull;
      HST16[msel * 32 + lcol] = r1 ? (unsigned short)0 : f2bf(hsel);
    }
    __syncthreads();  // B2: HST complete
    if (wv == 0 && t + 1 < TSTEPS) {
      unsigned long long* hqd = (unsigned long long*)hexd;
#pragma unroll
      for (int i = 0; i < 2; ++i) {
        int idx = i * 64 + lane;          // 0..127 u64 chunks (16 rows x 8)
        int row = idx >> 3, off = idx & 7;
        unsigned long long v = HST64[idx];
        __hip_atomic_store(hqd + (size_t)((pcur * 4 + bg) * 16 + row) * 128 +
                               cg * 8 + off,
                           v, __ATOMIC_RELAXED, __HIP_MEMORY_SCOPE_AGENT);
      }
      asm volatile("s_waitcnt vmcnt(0)" ::: "memory");  // data at MALL
      if (lane == 0)
        __hip_atomic_store(&flg[(bg * 16 + cg) * 16], (unsigned)(t + 1),
                           __ATOMIC_RELAXED, __HIP_MEMORY_SCOPE_AGENT);
    }

    // y store off the critical path
    y[((size_t)t * BATCH + bg * 16 + msel) * CDIM + cglob] = hsel;

#pragma unroll
    for (int q = 0; q < 4; ++q) xgc[q] = xgn[q];
  }
}

extern "C" void kernel_launch(void* const* d_in, const int* in_sizes, int n_in,
                              void* d_out, int out_size, void* d_ws, size_t ws_size,
                              hipStream_t stream) {
  (void)in_sizes; (void)n_in; (void)out_size;
  const float* x = (const float*)d_in[0];
  const void* rstp = (const void*)d_in[1];
  const float* h0 = (const float*)d_in[2];
  const float* c0 = (const float*)d_in[3];
  const float* wih = (const float*)d_in[4];
  const float* whh = (const float*)d_in[5];
  const float* bih = (const float*)d_in[6];
  const float* bhh = (const float*)d_in[7];
  float* y = (float*)d_out;

  if (ws_size < WS_NEED) return;  // diagnosable clean failure

  unsigned short* xgp = (unsigned short*)d_ws;
  unsigned short* hexd = (unsigned short*)((char*)d_ws + HEX_OFF);
  unsigned* flg = (unsigned*)((char*)d_ws + FLG_OFF);

  // reset flags every call (graph-safe; monotone within a call)
  (void)hipMemsetAsync((char*)d_ws + FLG_OFF, 0, FLG_BYTES, stream);

  // pre-pass: xg = x @ W_ih^T + bih + bhh   (8192 blocks: 512 bm x 16 bn)
  xg_prepass<<<dim3(8192), dim3(256), 0, stream>>>(x, wih, bih, bhh, xgp);

  (void)hipFuncSetAttribute(reinterpret_cast<const void*>(rlstm_seq),
                            hipFuncAttributeMaxDynamicSharedMemorySize, SMEM_BYTES);
  void* args[] = {(void*)&rstp, (void*)&h0, (void*)&c0, (void*)&whh,
                  (void*)&y,    (void*)&xgp, (void*)&hexd, (void*)&flg};
  (void)hipLaunchCooperativeKernel((void*)rlstm_seq, dim3(SEQ_BLOCKS),
                                   dim3(SEQ_THREADS), args, SMEM_BYTES, stream);
}

// Round 10
// 2295.968 us; speedup vs baseline: 3.9131x; 2.0967x over previous
//
#include <hip/hip_runtime.h>
#include <math.h>

typedef __attribute__((ext_vector_type(8))) short short8;
typedef __attribute__((ext_vector_type(4))) float f32x4;

#define TSTEPS 1024
#define BATCH  64
#define CDIM   512
#define NGATE  2048
#define CAP    512   // segments per group-chunk (LDS c-state capacity)

// ---- workspace layout ----
#define XG2_BYTES  ((size_t)16 * 65536 * 128 * 2)     // 256 MiB, cg-major
#define HEXB_OFF   XG2_BYTES
#define HEXB_BYTES ((size_t)16 * 2 * CAP * 1024)      // 16 MiB h exchange
#define GSEG_OFF   (HEXB_OFF + HEXB_BYTES)
#define GSEG_BYTES ((size_t)65536 * 4)
#define GCNT_OFF   (GSEG_OFF + GSEG_BYTES)
#define GCNT_BYTES (1024 * 4)
#define FLG_OFF    (GCNT_OFF + GCNT_BYTES)
#define FLG_BYTES  (256 * 16 * 4)
#define SEGT_OFF   (FLG_OFF + FLG_BYTES)
#define SEGT_BYTES ((size_t)64 * 1024 * 4)
#define WS_NEED    (SEGT_OFF + SEGT_BYTES)

// ---- main kernel LDS map (dynamic): ----
// HA dbuf 2x16KB @0 ; CSEG f32[512][32] @32768 ; HST bf16[2][16][32] @98304 ;
// GC u32[1024] @100352 ; SEGL u32[512] @104448  => 106496 B (forces 1 block/CU)
#define SMEM_BYTES 106496

__device__ __forceinline__ unsigned short f2bf(float x) {
  unsigned u = __builtin_bit_cast(unsigned, x);
  unsigned r = (u + 0x7FFFu + ((u >> 16) & 1u)) >> 16;
  return (unsigned short)r;
}
__device__ __forceinline__ float bf2f(unsigned short b) {
  unsigned u = ((unsigned)b) << 16;
  return __builtin_bit_cast(float, u);
}
__device__ __forceinline__ short8 pack8(float4 lo, float4 hi) {
  short8 r;
  r[0] = (short)f2bf(lo.x); r[1] = (short)f2bf(lo.y);
  r[2] = (short)f2bf(lo.z); r[3] = (short)f2bf(lo.w);
  r[4] = (short)f2bf(hi.x); r[5] = (short)f2bf(hi.y);
  r[6] = (short)f2bf(hi.z); r[7] = (short)f2bf(hi.w);
  return r;
}
__device__ __forceinline__ float sigm(float z) { return 1.0f / (1.0f + __expf(-z)); }
__device__ __forceinline__ float tanh_f(float x) {
  return 2.0f / (1.0f + __expf(-2.0f * x)) - 1.0f;
}

// poll 15 peer flags (own block ordered via vmcnt+barrier before post)
__device__ __forceinline__ void pollg(const unsigned* flg, int g, int cg,
                                      unsigned tgt, int lane) {
  const int idx = lane & 15;
  int rnd = 0;
  while (true) {
    unsigned v = (idx == cg)
                     ? 0xffffffffu
                     : __hip_atomic_load(&flg[(g * 16 + idx) * 16],
                                         __ATOMIC_RELAXED, __HIP_MEMORY_SCOPE_AGENT);
    if (__all((int)(v >= tgt))) break;
    if (rnd++) __builtin_amdgcn_s_sleep(1);
  }
  asm volatile("" ::: "memory");
}

__device__ __forceinline__ void flush_hst(const unsigned long long* HST64,
                                          unsigned short* hexb, int g, int dph,
                                          int i0, int M, int p, int lane, int cg) {
  const int rr = lane >> 2, pt = lane & 3;
  const int i = i0 + rr;
  if (i < M) {
    const unsigned long long* s = HST64 + p * 128 + rr * 8 + pt * 2;
    unsigned long long* d = (unsigned long long*)hexb +
        ((size_t)(g * 2 + dph) * CAP + i) * 128 + cg * 8 + pt * 2;
    __hip_atomic_store(d, s[0], __ATOMIC_RELAXED, __HIP_MEMORY_SCOPE_AGENT);
    __hip_atomic_store(d + 1, s[1], __ATOMIC_RELAXED, __HIP_MEMORY_SCOPE_AGENT);
  }
}

// ============ kernel 0: segment extraction + counting sort by length desc ====
// GSEG[rank] packed: len(11)<<17 | start(10)<<7 | b(6)<<1 | seed(1).
// Rank p sorted by len desc; group g owns ranks p%16==g. GCNT[r] = #len>r.
__global__ __launch_bounds__(512) void seg_setup(const void* __restrict__ rst,
    unsigned* __restrict__ GSEG, unsigned* __restrict__ GCNT,
    unsigned* __restrict__ SEGT) {
  __shared__ unsigned long long RM[1024];
  __shared__ unsigned hist[1025], GCl[1025], cur[1025];
  __shared__ unsigned nsegb[64];
  __shared__ int s_oki, s_okf, s_oddnz;
  const int tid = threadIdx.x, lane = tid & 63, wv = tid >> 6;
  if (tid == 0) { s_oki = 1; s_okf = 1; s_oddnz = 0; }
  __syncthreads();
  {
    int oki = 1, okf = 1, oddnz = 0;
    for (int i = tid; i < 1024; i += 512) {
      unsigned v = ((const unsigned*)rst)[i];
      oki &= (v <= 1u);
      okf &= (v == 0u || v == 0x3F800000u);
      if ((i & 1) && v != 0u) oddnz = 1;
    }
    if (!oki) atomicAnd(&s_oki, 0);
    if (!okf) atomicAnd(&s_okf, 0);
    if (oddnz) atomicOr(&s_oddnz, 1);
  }
  __syncthreads();
  const int mode = s_oki ? (s_oddnz ? 0 : 3) : (s_okf ? 2 : 1);
  for (int tt = wv; tt < 1024; tt += 8) {
    int idx = tt * BATCH + lane;
    bool r;
    if (mode == 0)      r = ((const int*)rst)[idx] != 0;
    else if (mode == 1) r = ((const unsigned char*)rst)[idx] != 0;
    else if (mode == 2) r = ((const float*)rst)[idx] != 0.0f;
    else                r = ((const int*)rst)[2 * idx] != 0;
    unsigned long long bm = __ballot((int)r);
    if (lane == 0) RM[tt] = bm;
  }
  for (int i = tid; i < 1025; i += 512) { hist[i] = 0; cur[i] = 0; }
  __syncthreads();
  if (tid < 64) {
    int b = tid; unsigned cnt = 0; int s = 0;
    unsigned seed0 = ((RM[0] >> b) & 1ull) ? 0u : 1u;
    for (int t = 1; t < 1024; ++t) {
      if ((RM[t] >> b) & 1ull) {
        unsigned len = (unsigned)(t - s);
        unsigned sd = (s == 0) ? seed0 : 0u;
        SEGT[b * 1024 + cnt++] = (len << 17) | ((unsigned)s << 7) | ((unsigned)b << 1) | sd;
        atomicAdd(&hist[len], 1u);
        s = t;
      }
    }
    { unsigned len = (unsigned)(1024 - s);
      unsigned sd = (s == 0) ? seed0 : 0u;
      SEGT[b * 1024 + cnt++] = (len << 17) | ((unsigned)s << 7) | ((unsigned)b << 1) | sd;
      atomicAdd(&hist[len], 1u); }
    nsegb[b] = cnt;
  }
  __syncthreads();
  if (tid == 0) {
    unsigned acc = 0;
    for (int r = 1023; r >= 0; --r) { acc += hist[r + 1]; GCl[r] = acc; }
    GCl[1024] = 0;
  }
  __syncthreads();
  if (tid < 64) {
    int b = tid;
    for (unsigned k = 0; k < nsegb[b]; ++k) {
      unsigned v = SEGT[b * 1024 + k];
      unsigned len = v >> 17;
      unsigned p = GCl[len] + atomicAdd(&cur[len], 1u);
      GSEG[p] = v;
    }
  }
  __syncthreads();
  for (int i = tid; i < 1024; i += 512) GCNT[i] = GCl[i];
}

// ============ kernel 1: xg2[cg][t*64+b][128] = x@W_ih^T + biases (bf16) ======
__global__ __launch_bounds__(256, 2) void xg_prepass(
    const float* __restrict__ x, const float* __restrict__ wih,
    const float* __restrict__ bih, const float* __restrict__ bhh,
    unsigned short* __restrict__ xg2) {
  __shared__ __align__(16) char lds[32768];
  char* Al = lds;
  char* Bl = lds + 16384;
  const int tid = threadIdx.x;
  const int bid = blockIdx.x;
  const int bm = bid & 511, bn = bid >> 9;
  const int lane = tid & 63, wv = tid >> 6;
  const int wm = wv >> 1, wn = wv & 1;
  const int grp = lane >> 4, lr = lane & 15;

  f32x4 acc[4][4] = {};
  float bsum[4];
#pragma unroll
  for (int nt = 0; nt < 4; ++nt) {
    int n = bn * 128 + wn * 64 + nt * 16 + lr;
    bsum[nt] = bih[n] + bhh[n];
  }

  for (int kb = 0; kb < 8; ++kb) {
    __syncthreads();
#pragma unroll
    for (int c = 0; c < 4; ++c) {
      int gi = tid + c * 256;
      int row = gi >> 3, colc = (gi & 7) * 8;
      const float* sA = x + ((size_t)(bm * 128 + row)) * 512 + kb * 64 + colc;
      float4 lo = *(const float4*)sA, hi = *(const float4*)(sA + 4);
      *(short8*)(Al + row * 128 + ((colc * 2) ^ ((row & 7) << 4))) = pack8(lo, hi);
      const float* sB = wih + ((size_t)(bn * 128 + row)) * 512 + kb * 64 + colc;
      float4 lo2 = *(const float4*)sB, hi2 = *(const float4*)(sB + 4);
      *(short8*)(Bl + row * 128 + ((colc * 2) ^ ((row & 7) << 4))) = pack8(lo2, hi2);
    }
    __syncthreads();
#pragma unroll
    for (int kk = 0; kk < 2; ++kk) {
      short8 af[4], bf[4];
#pragma unroll
      for (int mt = 0; mt < 4; ++mt) {
        int r = wm * 64 + mt * 16 + lr;
        af[mt] = *(const short8*)(Al + r * 128 + ((kk * 64 + grp * 16) ^ ((r & 7) << 4)));
      }
#pragma unroll
      for (int nt = 0; nt < 4; ++nt) {
        int r = wn * 64 + nt * 16 + lr;
        bf[nt] = *(const short8*)(Bl + r * 128 + ((kk * 64 + grp * 16) ^ ((r & 7) << 4)));
      }
#pragma unroll
      for (int mt = 0; mt < 4; ++mt)
#pragma unroll
        for (int nt = 0; nt < 4; ++nt)
          acc[mt][nt] = __builtin_amdgcn_mfma_f32_16x16x32_bf16(af[mt], bf[nt],
                                                                acc[mt][nt], 0, 0, 0);
    }
  }
#pragma unroll
  for (int mt = 0; mt < 4; ++mt)
#pragma unroll
    for (int nt = 0; nt < 4; ++nt)
#pragma unroll
      for (int q = 0; q < 4; ++q) {
        int m = bm * 128 + wm * 64 + mt * 16 + grp * 4 + q;
        int n = bn * 128 + wn * 64 + nt * 16 + lr;
        int cg2 = (n >> 5) & 15;
        int loc = (n >> 9) * 32 + (n & 31);
        xg2[(size_t)cg2 * 8388608 + (size_t)m * 128 + loc] =
            f2bf(acc[mt][nt][q] + bsum[nt]);
      }
}

// ============ kernel 2: depth-parallel persistent LSTM ======================
// 256 blocks = 16 groups x 16 col-blocks. Group g, round r: active rows =
// clamp(ceil((GCNT[r]-g)/16) - chunk*CAP, 0, CAP), a prefix of its rank list.
__global__ __launch_bounds__(512, 1) void rlstm_seq(
    const float* __restrict__ h0, const float* __restrict__ c0,
    const float* __restrict__ whh, float* __restrict__ y,
    const unsigned short* __restrict__ xg2, unsigned short* __restrict__ hexb,
    unsigned* __restrict__ flg, const unsigned* __restrict__ GSEG,
    const unsigned* __restrict__ GCNT) {
  extern __shared__ __align__(16) char smem[];
  float* CSEG = (float*)(smem + 32768);
  unsigned short* HST16 = (unsigned short*)(smem + 98304);
  unsigned long long* HST64 = (unsigned long long*)(smem + 98304);
  unsigned* GC = (unsigned*)(smem + 100352);
  unsigned* SEGL = (unsigned*)(smem + 104448);

  const int tid = threadIdx.x, bid = blockIdx.x;
  const int g = bid >> 4, cg = bid & 15;
  const int lane = tid & 63, wv = tid >> 6;
  const int grp = lane >> 4, lr = lane & 15;
  const int gt = lr >> 2, j = lr & 3;
  const int lcol = wv * 4 + j;
  const int cglob = cg * 32 + lcol;
  const int nglob = gt * CDIM + cglob;
  const int srow = 2 * wv + (lane >> 5);
  const int wcol = lane & 31;

  short8 wfrag[16];
#pragma unroll
  for (int kk = 0; kk < 16; ++kk) {
    const float* s = whh + (size_t)nglob * CDIM + kk * 32 + grp * 8;
    float4 lo = *(const float4*)s, hi = *(const float4*)(s + 4);
    wfrag[kk] = pack8(lo, hi);
  }
  for (int i = tid; i < 1024; i += 512) GC[i] = GCNT[i];
  __syncthreads();

  const unsigned G0 = GC[0];
  const unsigned totg = (G0 > (unsigned)g) ? ((G0 - g + 15u) >> 4) : 0u;
  const int nchunks = (int)((totg + CAP - 1) / CAP);
  unsigned fv = 0;

  for (int chunk = 0; chunk < nchunks; ++chunk) {
    const unsigned cb = (unsigned)chunk * CAP;
    int M0;
    { unsigned t2 = totg;
      M0 = (t2 > cb) ? (int)((t2 - cb > CAP) ? CAP : (t2 - cb)) : 0; }
    if (M0 == 0) break;
    if (fv) pollg(flg, g, cg, fv, lane);   // prior chunk fully consumed

    // ---- seed phase 0 (h at segment start) + CSEG + SEGL ----
    for (int i = tid >> 4; i < M0; i += 32) {
      int c2 = (tid & 15) * 2;
      unsigned sv = GSEG[(size_t)(cb + i) * 16 + g];
      if ((tid & 15) == 0) SEGL[i] = sv;
      int b = (sv >> 1) & 63;
      float ha = 0.f, hb = 0.f, ca = 0.f, cbv = 0.f;
      if (sv & 1u) {
        const float* hp = h0 + (size_t)b * CDIM + cg * 32 + c2;
        ha = hp[0]; hb = hp[1];
        const float* cp = c0 + (size_t)b * CDIM + cg * 32 + c2;
        ca = cp[0]; cbv = cp[1];
      }
      CSEG[i * 32 + c2] = ca; CSEG[i * 32 + c2 + 1] = cbv;
      unsigned pk = (unsigned)f2bf(ha) | ((unsigned)f2bf(hb) << 16);
      unsigned* hp32 = (unsigned*)hexb +
          ((size_t)(g * 2 + 0) * CAP + i) * 256 + cg * 16 + (tid & 15);
      __hip_atomic_store(hp32, pk, __ATOMIC_RELAXED, __HIP_MEMORY_SCOPE_AGENT);
    }
    asm volatile("s_waitcnt vmcnt(0)" ::: "memory");
    __syncthreads();
    fv++;
    if (tid == 0)
      __hip_atomic_store(&flg[(g * 16 + cg) * 16], fv, __ATOMIC_RELAXED,
                         __HIP_MEMORY_SCOPE_AGENT);

    // ---- depth rounds ----
    for (int r = 0;; ++r) {
      if (r >= 1024) break;
      int M;
      { unsigned Gr = GC[r];
        unsigned t2 = (Gr > (unsigned)g) ? ((Gr - g + 15u) >> 4) : 0u;
        M = (t2 > cb) ? (int)((t2 - cb > CAP) ? CAP : (t2 - cb)) : 0; }
      if (M == 0) break;
      const int ph = r & 1;

      float xgv[4]; int vq[4]; int rowq[4];
      auto loadxg = [&](int i0) {
#pragma unroll
        for (int q = 0; q < 4; ++q) {
          int i = i0 + grp * 4 + q;
          if (i < M) {
            unsigned sv = SEGL[i];
            int b = (sv >> 1) & 63, s0 = (sv >> 7) & 1023;
            int rowm = (s0 + r) * BATCH + b;
            rowq[q] = rowm; vq[q] = 1;
            xgv[q] = bf2f(xg2[(size_t)cg * 8388608 + (size_t)rowm * 128 +
                              gt * 32 + lcol]);
          } else { vq[q] = 0; rowq[q] = 0; xgv[q] = 0.f; }
        }
      };
      loadxg(0);                        // HBM latency hides under poll
      pollg(flg, g, cg, fv, lane);

      int pend = -1, pi0 = 0;
      for (int i0 = 0; i0 < M; i0 += 16) {
        const int p = (i0 >> 4) & 1;
        if (i0 > 0) loadxg(i0);
        if (wv == 0 && pend >= 0)
          flush_hst(HST64, hexb, g, ph ^ 1, pi0, M, pend, lane, cg);
        // stage h_prev tile into LDS (swizzled)
        char* habuf = smem + p * 16384;
        { int i = i0 + srow;
          if (i < M) {
            const unsigned long long* hq = (const unsigned long long*)hexb +
                ((size_t)(g * 2 + ph) * CAP + i) * 128;
            unsigned long long v4[4];
#pragma unroll
            for (int k = 0; k < 4; ++k)
              v4[k] = __hip_atomic_load(hq + wcol + 32 * k, __ATOMIC_RELAXED,
                                        __HIP_MEMORY_SCOPE_AGENT);
#pragma unroll
            for (int k = 0; k < 4; ++k) {
              int col = wcol + 32 * k;
              *(unsigned long long*)(habuf + srow * 1024 +
                                     ((col * 8) ^ ((srow & 7) << 4))) = v4[k];
            }
          }
        }
        __syncthreads();
        // recurrent GEMM 16x16 over K=512, dual chains
        f32x4 acc0 = {0.f, 0.f, 0.f, 0.f}, acc1 = {0.f, 0.f, 0.f, 0.f};
#pragma unroll
        for (int kk = 0; kk < 16; ++kk) {
          short8 a = *(const short8*)(habuf + lr * 1024 +
                                      ((kk * 64 + grp * 16) ^ ((lr & 7) << 4)));
          if (kk & 1)
            acc1 = __builtin_amdgcn_mfma_f32_16x16x32_bf16(a, wfrag[kk], acc1, 0, 0, 0);
          else
            acc0 = __builtin_amdgcn_mfma_f32_16x16x32_bf16(a, wfrag[kk], acc0, 0, 0, 0);
        }
        f32x4 acc = acc0 + acc1;
        // in-register cell via butterfly; lane gt handles row grp*4+gt
        float hsel = 0.f; int hrow = 0, hv = 0;
#pragma unroll
        for (int q = 0; q < 4; ++q) {
          float v0f = acc[q] + xgv[q];
          float ex1 = __shfl_xor(v0f, 4);
          float a2 = (gt & 1) ? ex1 : v0f;
          float b2 = (gt & 1) ? v0f : ex1;
          float exA = __shfl_xor(a2, 8);
          float exB = __shfl_xor(b2, 8);
          float gi = (gt & 2) ? exA : a2;
          float gf = (gt & 2) ? exB : b2;
          float gg = (gt & 2) ? a2 : exA;
          float go = (gt & 2) ? b2 : exB;
          if (q == gt && vq[q]) {
            int i = i0 + grp * 4 + q;
            float cprev = CSEG[i * 32 + lcol];
            float cn = sigm(gf) * cprev + sigm(gi) * tanh_f(gg);
            CSEG[i * 32 + lcol] = cn;
            hsel = sigm(go) * tanh_f(cn);
            HST16[p * 512 + (grp * 4 + q) * 32 + lcol] = f2bf(hsel);
            hv = 1; hrow = rowq[q];
          }
        }
        __syncthreads();
        if (hv) y[(size_t)hrow * CDIM + cglob] = hsel;
        pend = p; pi0 = i0;
      }
      if (wv == 0) flush_hst(HST64, hexb, g, ph ^ 1, pi0, M, pend, lane, cg);
      asm volatile("s_waitcnt vmcnt(0)" ::: "memory");
      __syncthreads();                 // own stores complete before any wave proceeds
      fv++;
      if (tid == 0)
        __hip_atomic_store(&flg[(g * 16 + cg) * 16], fv, __ATOMIC_RELAXED,
                           __HIP_MEMORY_SCOPE_AGENT);
    }
  }
}

extern "C" void kernel_launch(void* const* d_in, const int* in_sizes, int n_in,
                              void* d_out, int out_size, void* d_ws, size_t ws_size,
                              hipStream_t stream) {
  (void)in_sizes; (void)n_in; (void)out_size;
  const float* x = (const float*)d_in[0];
  const void* rstp = (const void*)d_in[1];
  const float* h0 = (const float*)d_in[2];
  const float* c0 = (const float*)d_in[3];
  const float* wih = (const float*)d_in[4];
  const float* whh = (const float*)d_in[5];
  const float* bih = (const float*)d_in[6];
  const float* bhh = (const float*)d_in[7];
  float* y = (float*)d_out;

  if (ws_size < WS_NEED) return;  // diagnosable clean failure

  unsigned short* xg2 = (unsigned short*)d_ws;
  unsigned short* hexb = (unsigned short*)((char*)d_ws + HEXB_OFF);
  unsigned* GSEG = (unsigned*)((char*)d_ws + GSEG_OFF);
  unsigned* GCNT = (unsigned*)((char*)d_ws + GCNT_OFF);
  unsigned* flg = (unsigned*)((char*)d_ws + FLG_OFF);
  unsigned* SEGT = (unsigned*)((char*)d_ws + SEGT_OFF);

  (void)hipMemsetAsync((char*)d_ws + FLG_OFF, 0, FLG_BYTES, stream);

  seg_setup<<<dim3(1), dim3(512), 0, stream>>>(rstp, GSEG, GCNT, SEGT);
  xg_prepass<<<dim3(8192), dim3(256), 0, stream>>>(x, wih, bih, bhh, xg2);

  (void)hipFuncSetAttribute(reinterpret_cast<const void*>(rlstm_seq),
                            hipFuncAttributeMaxDynamicSharedMemorySize, SMEM_BYTES);
  void* args[] = {(void*)&h0,  (void*)&c0,   (void*)&whh, (void*)&y,
                  (void*)&xg2, (void*)&hexb, (void*)&flg, (void*)&GSEG,
                  (void*)&GCNT};
  (void)hipLaunchCooperativeKernel((void*)rlstm_seq, dim3(256), dim3(512), args,
                                   SMEM_BYTES, stream);
}

// Round 11
// 1897.512 us; speedup vs baseline: 4.7348x; 1.2100x over previous
//
#include <hip/hip_runtime.h>
#include <math.h>

typedef __attribute__((ext_vector_type(8))) short short8;
typedef __attribute__((ext_vector_type(4))) float f32x4;

#define TSTEPS 1024
#define BATCH  64
#define CDIM   512
#define CAP    512   // segments per group-chunk (LDS c-state capacity)

// ---- workspace layout (no xg buffer anymore) ----
#define HEXB_OFF   0
#define HEXB_BYTES ((size_t)16 * 2 * CAP * 1024)      // 16 MiB h exchange
#define GSEG_OFF   (HEXB_OFF + HEXB_BYTES)
#define GSEG_BYTES ((size_t)65536 * 4)
#define GCNT_OFF   (GSEG_OFF + GSEG_BYTES)
#define GCNT_BYTES (1024 * 4)
#define FLG_OFF    (GCNT_OFF + GCNT_BYTES)
#define FLG_BYTES  (256 * 16 * 4)
#define SEGT_OFF   (FLG_OFF + FLG_BYTES)
#define SEGT_BYTES ((size_t)64 * 1024 * 4)
#define WS_NEED    (SEGT_OFF + SEGT_BYTES)

// ---- main kernel LDS map (dynamic, bytes): ----
// HA dbuf 2x16K @0 ; XA dbuf 2x16K @32768 ; CSEG f32[512][32] @65536 ;
// HST bf16[2][16][32] @131072 ; GC u32[1024] @133120 ; SEGL u32[512] @137216
#define SMEM_BYTES 139264   // > 81920 -> 1 block/CU

__device__ __forceinline__ unsigned short f2bf(float x) {
  unsigned u = __builtin_bit_cast(unsigned, x);
  unsigned r = (u + 0x7FFFu + ((u >> 16) & 1u)) >> 16;
  return (unsigned short)r;
}
__device__ __forceinline__ short8 pack8(float4 lo, float4 hi) {
  short8 r;
  r[0] = (short)f2bf(lo.x); r[1] = (short)f2bf(lo.y);
  r[2] = (short)f2bf(lo.z); r[3] = (short)f2bf(lo.w);
  r[4] = (short)f2bf(hi.x); r[5] = (short)f2bf(hi.y);
  r[6] = (short)f2bf(hi.z); r[7] = (short)f2bf(hi.w);
  return r;
}
__device__ __forceinline__ float sigm(float z) { return 1.0f / (1.0f + __expf(-z)); }
__device__ __forceinline__ float tanh_f(float x) {
  return 2.0f / (1.0f + __expf(-2.0f * x)) - 1.0f;
}

// poll 15 peer flags (own block ordered via vmcnt+barrier before post)
__device__ __forceinline__ void pollg(const unsigned* flg, int g, int cg,
                                      unsigned tgt, int lane) {
  const int idx = lane & 15;
  int rnd = 0;
  while (true) {
    unsigned v = (idx == cg)
                     ? 0xffffffffu
                     : __hip_atomic_load(&flg[(g * 16 + idx) * 16],
                                         __ATOMIC_RELAXED, __HIP_MEMORY_SCOPE_AGENT);
    if (__all((int)(v >= tgt))) break;
    if (rnd++) __builtin_amdgcn_s_sleep(1);
  }
  asm volatile("" ::: "memory");
}

__device__ __forceinline__ void flush_hst(const unsigned long long* HST64,
                                          unsigned short* hexb, int g, int dph,
                                          int i0, int M, int p, int lane, int cg) {
  const int rr = lane >> 2, pt = lane & 3;
  const int i = i0 + rr;
  if (i < M) {
    const unsigned long long* s = HST64 + p * 128 + rr * 8 + pt * 2;
    unsigned long long* d = (unsigned long long*)hexb +
        ((size_t)(g * 2 + dph) * CAP + i) * 128 + cg * 8 + pt * 2;
    __hip_atomic_store(d, s[0], __ATOMIC_RELAXED, __HIP_MEMORY_SCOPE_AGENT);
    __hip_atomic_store(d + 1, s[1], __ATOMIC_RELAXED, __HIP_MEMORY_SCOPE_AGENT);
  }
}

// ============ kernel 0: segment extraction + counting sort by length desc ====
// GSEG[rank] packed: len(11)<<17 | start(10)<<7 | b(6)<<1 | seed(1).
// Rank p sorted by len desc; group g owns ranks p%16==g. GCNT[r] = #len>r.
__global__ __launch_bounds__(512) void seg_setup(const void* __restrict__ rst,
    unsigned* __restrict__ GSEG, unsigned* __restrict__ GCNT,
    unsigned* __restrict__ SEGT) {
  __shared__ unsigned long long RM[1024];
  __shared__ unsigned hist[1025], GCl[1025], cur[1025];
  __shared__ unsigned nsegb[64];
  __shared__ int s_oki, s_okf, s_oddnz;
  const int tid = threadIdx.x, lane = tid & 63, wv = tid >> 6;
  if (tid == 0) { s_oki = 1; s_okf = 1; s_oddnz = 0; }
  __syncthreads();
  {
    int oki = 1, okf = 1, oddnz = 0;
    for (int i = tid; i < 1024; i += 512) {
      unsigned v = ((const unsigned*)rst)[i];
      oki &= (v <= 1u);
      okf &= (v == 0u || v == 0x3F800000u);
      if ((i & 1) && v != 0u) oddnz = 1;
    }
    if (!oki) atomicAnd(&s_oki, 0);
    if (!okf) atomicAnd(&s_okf, 0);
    if (oddnz) atomicOr(&s_oddnz, 1);
  }
  __syncthreads();
  const int mode = s_oki ? (s_oddnz ? 0 : 3) : (s_okf ? 2 : 1);
  for (int tt = wv; tt < 1024; tt += 8) {
    int idx = tt * BATCH + lane;
    bool r;
    if (mode == 0)      r = ((const int*)rst)[idx] != 0;
    else if (mode == 1) r = ((const unsigned char*)rst)[idx] != 0;
    else if (mode == 2) r = ((const float*)rst)[idx] != 0.0f;
    else                r = ((const int*)rst)[2 * idx] != 0;
    unsigned long long bm = __ballot((int)r);
    if (lane == 0) RM[tt] = bm;
  }
  for (int i = tid; i < 1025; i += 512) { hist[i] = 0; cur[i] = 0; }
  __syncthreads();
  if (tid < 64) {
    int b = tid; unsigned cnt = 0; int s = 0;
    unsigned seed0 = ((RM[0] >> b) & 1ull) ? 0u : 1u;
    for (int t = 1; t < 1024; ++t) {
      if ((RM[t] >> b) & 1ull) {
        unsigned len = (unsigned)(t - s);
        unsigned sd = (s == 0) ? seed0 : 0u;
        SEGT[b * 1024 + cnt++] = (len << 17) | ((unsigned)s << 7) | ((unsigned)b << 1) | sd;
        atomicAdd(&hist[len], 1u);
        s = t;
      }
    }
    { unsigned len = (unsigned)(1024 - s);
      unsigned sd = (s == 0) ? seed0 : 0u;
      SEGT[b * 1024 + cnt++] = (len << 17) | ((unsigned)s << 7) | ((unsigned)b << 1) | sd;
      atomicAdd(&hist[len], 1u); }
    nsegb[b] = cnt;
  }
  __syncthreads();
  if (tid == 0) {
    unsigned acc = 0;
    for (int r = 1023; r >= 0; --r) { acc += hist[r + 1]; GCl[r] = acc; }
    GCl[1024] = 0;
  }
  __syncthreads();
  if (tid < 64) {
    int b = tid;
    for (unsigned k = 0; k < nsegb[b]; ++k) {
      unsigned v = SEGT[b * 1024 + k];
      unsigned len = v >> 17;
      unsigned p = GCl[len] + atomicAdd(&cur[len], 1u);
      GSEG[p] = v;
    }
  }
  __syncthreads();
  for (int i = tid; i < 1024; i += 512) GCNT[i] = GCl[i];
}

// ============ kernel 1: depth-parallel persistent LSTM (fused x-projection) ==
// 256 blocks = 16 groups x 16 col-blocks. Group g, round r: active rows =
// clamp(ceil((GCNT[r]-g)/16) - chunk*CAP, 0, CAP), a prefix of its rank list.
// Per tile: stage x rows (L3) + h rows (exchange) -> 32 MFMA (W_hh + W_ih,
// both register-resident) -> in-register cell -> coalesced h flush.
__global__ __launch_bounds__(512, 1) void rlstm_seq(
    const float* __restrict__ x, const float* __restrict__ h0,
    const float* __restrict__ c0, const float* __restrict__ whh,
    const float* __restrict__ wih, const float* __restrict__ bih,
    const float* __restrict__ bhh, float* __restrict__ y,
    unsigned short* __restrict__ hexb, unsigned* __restrict__ flg,
    const unsigned* __restrict__ GSEG, const unsigned* __restrict__ GCNT) {
  extern __shared__ __align__(16) char smem[];
  float* CSEG = (float*)(smem + 65536);
  unsigned short* HST16 = (unsigned short*)(smem + 131072);
  unsigned long long* HST64 = (unsigned long long*)(smem + 131072);
  unsigned* GC = (unsigned*)(smem + 133120);
  unsigned* SEGL = (unsigned*)(smem + 137216);

  const int tid = threadIdx.x, bid = blockIdx.x;
  const int g = bid >> 4, cg = bid & 15;
  const int lane = tid & 63, wv = tid >> 6;
  const int grp = lane >> 4, lr = lane & 15;
  const int gt = lr >> 2, j = lr & 3;
  const int lcol = wv * 4 + j;
  const int cglob = cg * 32 + lcol;
  const int nglob = gt * CDIM + cglob;
  const int srow = 2 * wv + (lane >> 5);
  const int wcol = lane & 31;

  // both weight slices register-resident: 128 VGPR/wave
  short8 wfrag[16], wfrag2[16];
#pragma unroll
  for (int kk = 0; kk < 16; ++kk) {
    const float* s = whh + (size_t)nglob * CDIM + kk * 32 + grp * 8;
    float4 lo = *(const float4*)s, hi = *(const float4*)(s + 4);
    wfrag[kk] = pack8(lo, hi);
    const float* s2 = wih + (size_t)nglob * CDIM + kk * 32 + grp * 8;
    float4 lo2 = *(const float4*)s2, hi2 = *(const float4*)(s2 + 4);
    wfrag2[kk] = pack8(lo2, hi2);
  }
  const float bsum = bih[nglob] + bhh[nglob];

  for (int i = tid; i < 1024; i += 512) GC[i] = GCNT[i];
  __syncthreads();

  const unsigned G0 = GC[0];
  const unsigned totg = (G0 > (unsigned)g) ? ((G0 - g + 15u) >> 4) : 0u;
  const int nchunks = (int)((totg + CAP - 1) / CAP);
  unsigned fv = 0;

  for (int chunk = 0; chunk < nchunks; ++chunk) {
    const unsigned cb = (unsigned)chunk * CAP;
    int M0;
    { unsigned t2 = totg;
      M0 = (t2 > cb) ? (int)((t2 - cb > CAP) ? CAP : (t2 - cb)) : 0; }
    if (M0 == 0) break;
    if (fv) pollg(flg, g, cg, fv, lane);   // prior chunk fully consumed

    // ---- seed phase 0 (h at segment start) + CSEG + SEGL ----
    for (int i = tid >> 4; i < M0; i += 32) {
      int c2 = (tid & 15) * 2;
      unsigned sv = GSEG[(size_t)(cb + i) * 16 + g];
      if ((tid & 15) == 0) SEGL[i] = sv;
      int b = (sv >> 1) & 63;
      float ha = 0.f, hb = 0.f, ca = 0.f, cbv = 0.f;
      if (sv & 1u) {
        const float* hp = h0 + (size_t)b * CDIM + cg * 32 + c2;
        ha = hp[0]; hb = hp[1];
        const float* cp = c0 + (size_t)b * CDIM + cg * 32 + c2;
        ca = cp[0]; cbv = cp[1];
      }
      CSEG[i * 32 + c2] = ca; CSEG[i * 32 + c2 + 1] = cbv;
      unsigned pk = (unsigned)f2bf(ha) | ((unsigned)f2bf(hb) << 16);
      unsigned* hp32 = (unsigned*)hexb +
          ((size_t)(g * 2 + 0) * CAP + i) * 256 + cg * 16 + (tid & 15);
      __hip_atomic_store(hp32, pk, __ATOMIC_RELAXED, __HIP_MEMORY_SCOPE_AGENT);
    }
    asm volatile("s_waitcnt vmcnt(0)" ::: "memory");
    __syncthreads();
    fv++;
    if (tid == 0)
      __hip_atomic_store(&flg[(g * 16 + cg) * 16], fv, __ATOMIC_RELAXED,
                         __HIP_MEMORY_SCOPE_AGENT);

    // ---- depth rounds ----
    for (int r = 0;; ++r) {
      if (r >= 1024) break;
      int M;
      { unsigned Gr = GC[r];
        unsigned t2 = (Gr > (unsigned)g) ? ((Gr - g + 15u) >> 4) : 0u;
        M = (t2 > cb) ? (int)((t2 - cb > CAP) ? CAP : (t2 - cb)) : 0; }
      if (M == 0) break;
      const int ph = r & 1;

      pollg(flg, g, cg, fv, lane);

      int pend = -1, pi0 = 0;
      for (int i0 = 0; i0 < M; i0 += 16) {
        const int p = (i0 >> 4) & 1;
        // stage x rows for this tile into XA[p] (L3-resident gather)
        { int i = i0 + srow;
          if (i < M) {
            unsigned sv = SEGL[i];
            int b = (sv >> 1) & 63, s0 = (sv >> 7) & 1023;
            const float* xr = x + ((size_t)(s0 + r) * BATCH + b) * CDIM;
            char* xabuf = smem + 32768 + p * 16384;
#pragma unroll
            for (int k2 = 0; k2 < 2; ++k2) {
              int pp = wcol + 32 * k2;
              float4 lo = *(const float4*)(xr + pp * 8);
              float4 hi = *(const float4*)(xr + pp * 8 + 4);
              *(short8*)(xabuf + srow * 1024 + ((pp * 16) ^ ((srow & 7) << 4))) =
                  pack8(lo, hi);
            }
          }
        }
        if (wv == 0 && pend >= 0)
          flush_hst(HST64, hexb, g, ph ^ 1, pi0, M, pend, lane, cg);
        // stage h_prev tile into LDS (swizzled)
        char* habuf = smem + p * 16384;
        { int i = i0 + srow;
          if (i < M) {
            const unsigned long long* hq = (const unsigned long long*)hexb +
                ((size_t)(g * 2 + ph) * CAP + i) * 128;
            unsigned long long v4[4];
#pragma unroll
            for (int k = 0; k < 4; ++k)
              v4[k] = __hip_atomic_load(hq + wcol + 32 * k, __ATOMIC_RELAXED,
                                        __HIP_MEMORY_SCOPE_AGENT);
#pragma unroll
            for (int k = 0; k < 4; ++k) {
              int col = wcol + 32 * k;
              *(unsigned long long*)(habuf + srow * 1024 +
                                     ((col * 8) ^ ((srow & 7) << 4))) = v4[k];
            }
          }
        }
        __syncthreads();
        // row validity + y rows for this tile
        int vq[4], rowq[4];
#pragma unroll
        for (int q = 0; q < 4; ++q) {
          int i = i0 + grp * 4 + q;
          if (i < M) {
            unsigned sv = SEGL[i];
            rowq[q] = (int)((((sv >> 7) & 1023) + r) * BATCH + ((sv >> 1) & 63));
            vq[q] = 1;
          } else { vq[q] = 0; rowq[q] = 0; }
        }
        // recurrent + input GEMMs: 16x16 over K=512, dual chains each
        char* xabuf = smem + 32768 + p * 16384;
        f32x4 h0a = {0.f,0.f,0.f,0.f}, h1a = {0.f,0.f,0.f,0.f};
        f32x4 x0a = {0.f,0.f,0.f,0.f}, x1a = {0.f,0.f,0.f,0.f};
#pragma unroll
        for (int kk = 0; kk < 16; ++kk) {
          const int aoff = ((kk * 64 + grp * 16) ^ ((lr & 7) << 4));
          short8 a = *(const short8*)(habuf + lr * 1024 + aoff);
          short8 ax = *(const short8*)(xabuf + lr * 1024 + aoff);
          if (kk & 1) {
            h1a = __builtin_amdgcn_mfma_f32_16x16x32_bf16(a, wfrag[kk], h1a, 0, 0, 0);
            x1a = __builtin_amdgcn_mfma_f32_16x16x32_bf16(ax, wfrag2[kk], x1a, 0, 0, 0);
          } else {
            h0a = __builtin_amdgcn_mfma_f32_16x16x32_bf16(a, wfrag[kk], h0a, 0, 0, 0);
            x0a = __builtin_amdgcn_mfma_f32_16x16x32_bf16(ax, wfrag2[kk], x0a, 0, 0, 0);
          }
        }
        f32x4 acc = (h0a + h1a) + (x0a + x1a);
        // in-register cell via butterfly; lane gt handles row grp*4+gt
        float hsel = 0.f; int hrow = 0, hv = 0;
#pragma unroll
        for (int q = 0; q < 4; ++q) {
          float v0f = acc[q] + bsum;
          float ex1 = __shfl_xor(v0f, 4);
          float a2 = (gt & 1) ? ex1 : v0f;
          float b2 = (gt & 1) ? v0f : ex1;
          float exA = __shfl_xor(a2, 8);
          float exB = __shfl_xor(b2, 8);
          float gi = (gt & 2) ? exA : a2;
          float gf = (gt & 2) ? exB : b2;
          float gg = (gt & 2) ? a2 : exA;
          float go = (gt & 2) ? b2 : exB;
          if (q == gt && vq[q]) {
            int i = i0 + grp * 4 + q;
            float cprev = CSEG[i * 32 + lcol];
            float cn = sigm(gf) * cprev + sigm(gi) * tanh_f(gg);
            CSEG[i * 32 + lcol] = cn;
            hsel = sigm(go) * tanh_f(cn);
            HST16[p * 512 + (grp * 4 + q) * 32 + lcol] = f2bf(hsel);
            hv = 1; hrow = rowq[q];
          }
        }
        __syncthreads();
        if (hv) y[(size_t)hrow * CDIM + cglob] = hsel;
        pend = p; pi0 = i0;
      }
      if (wv == 0) flush_hst(HST64, hexb, g, ph ^ 1, pi0, M, pend, lane, cg);
      asm volatile("s_waitcnt vmcnt(0)" ::: "memory");
      __syncthreads();                 // own stores complete before any wave proceeds
      fv++;
      if (tid == 0)
        __hip_atomic_store(&flg[(g * 16 + cg) * 16], fv, __ATOMIC_RELAXED,
                           __HIP_MEMORY_SCOPE_AGENT);
    }
  }
}

extern "C" void kernel_launch(void* const* d_in, const int* in_sizes, int n_in,
                              void* d_out, int out_size, void* d_ws, size_t ws_size,
                              hipStream_t stream) {
  (void)in_sizes; (void)n_in; (void)out_size;
  const float* x = (const float*)d_in[0];
  const void* rstp = (const void*)d_in[1];
  const float* h0 = (const float*)d_in[2];
  const float* c0 = (const float*)d_in[3];
  const float* wih = (const float*)d_in[4];
  const float* whh = (const float*)d_in[5];
  const float* bih = (const float*)d_in[6];
  const float* bhh = (const float*)d_in[7];
  float* y = (float*)d_out;

  if (ws_size < WS_NEED) return;  // diagnosable clean failure

  unsigned short* hexb = (unsigned short*)((char*)d_ws + HEXB_OFF);
  unsigned* GSEG = (unsigned*)((char*)d_ws + GSEG_OFF);
  unsigned* GCNT = (unsigned*)((char*)d_ws + GCNT_OFF);
  unsigned* flg = (unsigned*)((char*)d_ws + FLG_OFF);
  unsigned* SEGT = (unsigned*)((char*)d_ws + SEGT_OFF);

  (void)hipMemsetAsync((char*)d_ws + FLG_OFF, 0, FLG_BYTES, stream);

  seg_setup<<<dim3(1), dim3(512), 0, stream>>>(rstp, GSEG, GCNT, SEGT);

  (void)hipFuncSetAttribute(reinterpret_cast<const void*>(rlstm_seq),
                            hipFuncAttributeMaxDynamicSharedMemorySize, SMEM_BYTES);
  void* args[] = {(void*)&x,   (void*)&h0,   (void*)&c0,  (void*)&whh,
                  (void*)&wih, (void*)&bih,  (void*)&bhh, (void*)&y,
                  (void*)&hexb, (void*)&flg, (void*)&GSEG, (void*)&GCNT};
  (void)hipLaunchCooperativeKernel((void*)rlstm_seq, dim3(256), dim3(512), args,
                                   SMEM_BYTES, stream);
}

// Round 12
// 1815.918 us; speedup vs baseline: 4.9476x; 1.0449x over previous
//
#include <hip/hip_runtime.h>
#include <math.h>

typedef __attribute__((ext_vector_type(8))) short short8;
typedef __attribute__((ext_vector_type(4))) float f32x4;

#define TSTEPS 1024
#define BATCH  64
#define CDIM   512
#define CAP    256   // segments per group-chunk (ring-row capacity)
#define NPH    4     // ring phases

// ---- workspace layout ----
// HEXW: tagged u32 [16 groups][NPH][CAP rows][512 cols] = 32 MiB
#define HEXW_OFF   0
#define HEXW_BYTES ((size_t)16 * NPH * CAP * 512 * 4)
#define GSEG_OFF   (HEXW_OFF + HEXW_BYTES)
#define GSEG_BYTES ((size_t)65536 * 4)
#define GCNT_OFF   (GSEG_OFF + GSEG_BYTES)
#define GCNT_BYTES (1024 * 4)
#define FLG_OFF    (GCNT_OFF + GCNT_BYTES)
#define FLG_BYTES  (256 * 16 * 4)
#define SEGT_OFF   (FLG_OFF + FLG_BYTES)
#define SEGT_BYTES ((size_t)64 * 1024 * 4)
#define WS_NEED    (SEGT_OFF + SEGT_BYTES)

// ---- main kernel LDS map (dynamic, bytes) ----
// HA dbuf 2x16K @0 ; XA dbuf 2x16K @32768 ; CSEG f32[256][32] @65536 ;
// HST bf16[2][16][32] @98304 ; GC u32[1024] @100352 ; SEGL u32[256] @104448
#define SMEM_BYTES 105472   // > 81920 -> 1 block/CU

__device__ __forceinline__ unsigned short f2bf(float x) {
  unsigned u = __builtin_bit_cast(unsigned, x);
  unsigned r = (u + 0x7FFFu + ((u >> 16) & 1u)) >> 16;
  return (unsigned short)r;
}
__device__ __forceinline__ short8 pack8(float4 lo, float4 hi) {
  short8 r;
  r[0] = (short)f2bf(lo.x); r[1] = (short)f2bf(lo.y);
  r[2] = (short)f2bf(lo.z); r[3] = (short)f2bf(lo.w);
  r[4] = (short)f2bf(hi.x); r[5] = (short)f2bf(hi.y);
  r[6] = (short)f2bf(hi.z); r[7] = (short)f2bf(hi.w);
  return r;
}
__device__ __forceinline__ float sigm(float z) { return 1.0f / (1.0f + __expf(-z)); }
__device__ __forceinline__ float tanh_f(float x) {
  return 2.0f / (1.0f + __expf(-2.0f * x)) - 1.0f;
}

// chunk-boundary only: poll 15 peer flags
__device__ __forceinline__ void pollg(const unsigned* flg, int g, int cg,
                                      unsigned tgt, int lane) {
  const int idx = lane & 15;
  int rnd = 0;
  while (true) {
    unsigned v = (idx == cg)
                     ? 0xffffffffu
                     : __hip_atomic_load(&flg[(g * 16 + idx) * 16],
                                         __ATOMIC_RELAXED, __HIP_MEMORY_SCOPE_AGENT);
    if (__all((int)(v >= tgt))) break;
    if (rnd++) __builtin_amdgcn_s_sleep(1);
  }
  asm volatile("" ::: "memory");
}

// fire-and-forget tagged flush: rows i0..i0+15 (< Mn), this block's 32-col slice
__device__ __forceinline__ void flush_tag(const unsigned short* HST16,
                                          unsigned* hexw, int g, int phw, int i0,
                                          int Mn, int p, int lane, int cg,
                                          unsigned tg) {
  const int rr = lane >> 2, pt = lane & 3;
  const int i = i0 + rr;
  if (i < Mn) {
    const unsigned short* s = HST16 + p * 512 + rr * 32 + pt * 8;
    unsigned long long* d = (unsigned long long*)hexw +
        ((size_t)((g * NPH + phw) * CAP + i)) * 256 + cg * 16 + pt * 4;
#pragma unroll
    for (int jj = 0; jj < 4; ++jj) {
      unsigned lo = ((unsigned)s[2 * jj] << 16) | tg;
      unsigned hi = ((unsigned)s[2 * jj + 1] << 16) | tg;
      unsigned long long w = ((unsigned long long)hi << 32) | lo;
      __hip_atomic_store(d + jj, w, __ATOMIC_RELAXED, __HIP_MEMORY_SCOPE_AGENT);
    }
  }
}

// ============ kernel 0: segment extraction + counting sort by length desc ====
// GSEG[rank] packed: len(11)<<17 | start(10)<<7 | b(6)<<1 | seed(1).
// Rank p sorted by len desc; group g owns ranks p%16==g. GCNT[r] = #len>r.
__global__ __launch_bounds__(512) void seg_setup(const void* __restrict__ rst,
    unsigned* __restrict__ GSEG, unsigned* __restrict__ GCNT,
    unsigned* __restrict__ SEGT) {
  __shared__ unsigned long long RM[1024];
  __shared__ unsigned hist[1025], GCl[1025], cur[1025];
  __shared__ unsigned nsegb[64];
  __shared__ int s_oki, s_okf, s_oddnz;
  const int tid = threadIdx.x, lane = tid & 63, wv = tid >> 6;
  if (tid == 0) { s_oki = 1; s_okf = 1; s_oddnz = 0; }
  __syncthreads();
  {
    int oki = 1, okf = 1, oddnz = 0;
    for (int i = tid; i < 1024; i += 512) {
      unsigned v = ((const unsigned*)rst)[i];
      oki &= (v <= 1u);
      okf &= (v == 0u || v == 0x3F800000u);
      if ((i & 1) && v != 0u) oddnz = 1;
    }
    if (!oki) atomicAnd(&s_oki, 0);
    if (!okf) atomicAnd(&s_okf, 0);
    if (oddnz) atomicOr(&s_oddnz, 1);
  }
  __syncthreads();
  const int mode = s_oki ? (s_oddnz ? 0 : 3) : (s_okf ? 2 : 1);
  for (int tt = wv; tt < 1024; tt += 8) {
    int idx = tt * BATCH + lane;
    bool r;
    if (mode == 0)      r = ((const int*)rst)[idx] != 0;
    else if (mode == 1) r = ((const unsigned char*)rst)[idx] != 0;
    else if (mode == 2) r = ((const float*)rst)[idx] != 0.0f;
    else                r = ((const int*)rst)[2 * idx] != 0;
    unsigned long long bm = __ballot((int)r);
    if (lane == 0) RM[tt] = bm;
  }
  for (int i = tid; i < 1025; i += 512) { hist[i] = 0; cur[i] = 0; }
  __syncthreads();
  if (tid < 64) {
    int b = tid; unsigned cnt = 0; int s = 0;
    unsigned seed0 = ((RM[0] >> b) & 1ull) ? 0u : 1u;
    for (int t = 1; t < 1024; ++t) {
      if ((RM[t] >> b) & 1ull) {
        unsigned len = (unsigned)(t - s);
        unsigned sd = (s == 0) ? seed0 : 0u;
        SEGT[b * 1024 + cnt++] = (len << 17) | ((unsigned)s << 7) | ((unsigned)b << 1) | sd;
        atomicAdd(&hist[len], 1u);
        s = t;
      }
    }
    { unsigned len = (unsigned)(1024 - s);
      unsigned sd = (s == 0) ? seed0 : 0u;
      SEGT[b * 1024 + cnt++] = (len << 17) | ((unsigned)s << 7) | ((unsigned)b << 1) | sd;
      atomicAdd(&hist[len], 1u); }
    nsegb[b] = cnt;
  }
  __syncthreads();
  if (tid == 0) {
    unsigned acc = 0;
    for (int r = 1023; r >= 0; --r) { acc += hist[r + 1]; GCl[r] = acc; }
    GCl[1024] = 0;
  }
  __syncthreads();
  if (tid < 64) {
    int b = tid;
    for (unsigned k = 0; k < nsegb[b]; ++k) {
      unsigned v = SEGT[b * 1024 + k];
      unsigned len = v >> 17;
      unsigned p = GCl[len] + atomicAdd(&cur[len], 1u);
      GSEG[p] = v;
    }
  }
  __syncthreads();
  for (int i = tid; i < 1024; i += 512) GCNT[i] = GCl[i];
}

// ============ kernel 1: depth-parallel LSTM, tagged 4-phase ring exchange ====
__global__ __launch_bounds__(512, 1) void rlstm_seq(
    const float* __restrict__ x, const float* __restrict__ h0,
    const float* __restrict__ c0, const float* __restrict__ whh,
    const float* __restrict__ wih, const float* __restrict__ bih,
    const float* __restrict__ bhh, float* __restrict__ y,
    unsigned* __restrict__ hexw, unsigned* __restrict__ flg,
    const unsigned* __restrict__ GSEG, const unsigned* __restrict__ GCNT) {
  extern __shared__ __align__(16) char smem[];
  float* CSEG = (float*)(smem + 65536);
  unsigned short* HST16 = (unsigned short*)(smem + 98304);
  unsigned* GC = (unsigned*)(smem + 100352);
  unsigned* SEGL = (unsigned*)(smem + 104448);

  const int tid = threadIdx.x, bid = blockIdx.x;
  const int g = bid >> 4, cg = bid & 15;
  const int lane = tid & 63, wv = tid >> 6;
  const int grp = lane >> 4, lr = lane & 15;
  const int gt = lr >> 2, j = lr & 3;
  const int lcol = wv * 4 + j;
  const int cglob = cg * 32 + lcol;
  const int nglob = gt * CDIM + cglob;
  const int srow = 2 * wv + (lane >> 5);
  const int wcol = lane & 31;
  const int swz = (srow & 7) << 4;

  // both weight slices register-resident: 128 VGPR/wave
  short8 wfrag[16], wfrag2[16];
#pragma unroll
  for (int kk = 0; kk < 16; ++kk) {
    const float* s = whh + (size_t)nglob * CDIM + kk * 32 + grp * 8;
    float4 lo = *(const float4*)s, hi = *(const float4*)(s + 4);
    wfrag[kk] = pack8(lo, hi);
    const float* s2 = wih + (size_t)nglob * CDIM + kk * 32 + grp * 8;
    float4 lo2 = *(const float4*)s2, hi2 = *(const float4*)(s2 + 4);
    wfrag2[kk] = pack8(lo2, hi2);
  }
  const float bsum = bih[nglob] + bhh[nglob];

  for (int i = tid; i < 1024; i += 512) GC[i] = GCNT[i];
  __syncthreads();

  const unsigned G0 = GC[0];
  const unsigned totg = (G0 > (unsigned)g) ? ((G0 - g + 15u) >> 4) : 0u;
  const int nchunks = (int)((totg + CAP - 1) / CAP);
  unsigned tg = 0, fv = 0;

  for (int chunk = 0; chunk < nchunks; ++chunk) {
    const unsigned cb = (unsigned)chunk * CAP;
    int M0;
    { unsigned t2 = totg;
      M0 = (t2 > cb) ? (int)((t2 - cb > CAP) ? CAP : (t2 - cb)) : 0; }
    if (M0 == 0) break;
    if (chunk > 0) pollg(flg, g, cg, fv, lane);  // peers exited prior chunk

    ++tg;  // seed tag (consumed by round 0)
    // ---- seed phase 0 + CSEG + SEGL ----
    for (int i = tid >> 4; i < M0; i += 32) {
      int c2 = (tid & 15) * 2;
      unsigned sv = GSEG[(size_t)(cb + i) * 16 + g];
      if ((tid & 15) == 0) SEGL[i] = sv;
      int b = (sv >> 1) & 63;
      float ha = 0.f, hb = 0.f, ca = 0.f, cbv = 0.f;
      if (sv & 1u) {
        const float* hp = h0 + (size_t)b * CDIM + cg * 32 + c2;
        ha = hp[0]; hb = hp[1];
        const float* cp = c0 + (size_t)b * CDIM + cg * 32 + c2;
        ca = cp[0]; cbv = cp[1];
      }
      CSEG[i * 32 + c2] = ca; CSEG[i * 32 + c2 + 1] = cbv;
      unsigned lo = ((unsigned)f2bf(ha) << 16) | tg;
      unsigned hi2 = ((unsigned)f2bf(hb) << 16) | tg;
      unsigned long long w = ((unsigned long long)hi2 << 32) | lo;
      __hip_atomic_store((unsigned long long*)hexw +
                             ((size_t)(g * NPH + 0) * CAP + i) * 256 + cg * 16 +
                             (tid & 15),
                         w, __ATOMIC_RELAXED, __HIP_MEMORY_SCOPE_AGENT);
    }
    __syncthreads();  // SEGL/CSEG ready

    // ---- depth rounds ----
    for (int r = 0;; ++r) {
      if (r >= 1024) break;
      int M;
      { unsigned Gr = GC[r];
        unsigned t2 = (Gr > (unsigned)g) ? ((Gr - g + 15u) >> 4) : 0u;
        M = (t2 > cb) ? (int)((t2 - cb > CAP) ? CAP : (t2 - cb)) : 0; }
      if (M == 0) break;
      int Mn = 0;
      if (r + 1 < 1024) {
        unsigned Gn = GC[r + 1];
        unsigned t2 = (Gn > (unsigned)g) ? ((Gn - g + 15u) >> 4) : 0u;
        Mn = (t2 > cb) ? (int)((t2 - cb > CAP) ? CAP : (t2 - cb)) : 0;
      }
      const int ph = r & (NPH - 1), phw = (r + 1) & (NPH - 1);
      const unsigned wtg = tg + 1;

      int pend = -1, pi0 = 0;
      for (int i0 = 0; i0 < M; i0 += 16) {
        const int p = (i0 >> 4) & 1;
        // stage x rows for this tile into XA[p] (L3-resident gather)
        { int i = i0 + srow;
          if (i < M) {
            unsigned sv = SEGL[i];
            int b = (sv >> 1) & 63, s0 = (sv >> 7) & 1023;
            const float* xr = x + ((size_t)(s0 + r) * BATCH + b) * CDIM;
            char* xabuf = smem + 32768 + p * 16384;
#pragma unroll
            for (int k2 = 0; k2 < 2; ++k2) {
              int pp = wcol + 32 * k2;
              float4 lo = *(const float4*)(xr + pp * 8);
              float4 hi = *(const float4*)(xr + pp * 8 + 4);
              *(short8*)(xabuf + srow * 1024 + ((pp * 16) ^ swz)) = pack8(lo, hi);
            }
          }
        }
        if (wv == 0 && pend >= 0)
          flush_tag(HST16, hexw, g, phw, pi0, Mn, pend, lane, cg, wtg);
        // poll + stage h_prev tile (tagged words ARE the handshake)
        char* habuf = smem + p * 16384;
        { int i = i0 + srow;
          if (i < M) {
            const unsigned long long* hq = (const unsigned long long*)hexw +
                ((size_t)(g * NPH + ph) * CAP + i) * 256;
            unsigned long long v8[8];
            unsigned pn = 0xffu;
            int rnd = 0;
            do {
              if (rnd++) __builtin_amdgcn_s_sleep(1);
#pragma unroll
              for (int k = 0; k < 8; ++k)
                if (pn & (1u << k))
                  v8[k] = __hip_atomic_load(hq + wcol + 32 * k, __ATOMIC_RELAXED,
                                            __HIP_MEMORY_SCOPE_AGENT);
              unsigned np = 0;
#pragma unroll
              for (int k = 0; k < 8; ++k) {
                unsigned lo = (unsigned)v8[k];
                unsigned hi = (unsigned)(v8[k] >> 32);
                if (((lo ^ tg) | (hi ^ tg)) & 0xffffu) np |= 1u << k;
              }
              pn = np;
            } while (__any((int)pn));
#pragma unroll
            for (int k = 0; k < 8; ++k) {
              unsigned lo = (unsigned)v8[k];
              unsigned hi = (unsigned)(v8[k] >> 32);
              unsigned pk = (lo >> 16) | (hi & 0xffff0000u);
              int m = wcol + 32 * k;
              *(unsigned*)(habuf + srow * 1024 + ((m * 4) ^ swz)) = pk;
            }
          }
        }
        __syncthreads();
        // row validity + y rows
        int vq[4], rowq[4];
#pragma unroll
        for (int q = 0; q < 4; ++q) {
          int i = i0 + grp * 4 + q;
          if (i < M) {
            unsigned sv = SEGL[i];
            rowq[q] = (int)((((sv >> 7) & 1023) + r) * BATCH + ((sv >> 1) & 63));
            vq[q] = 1;
          } else { vq[q] = 0; rowq[q] = 0; }
        }
        // recurrent + input GEMMs: dual chains each
        char* xabuf = smem + 32768 + p * 16384;
        f32x4 h0a = {0.f,0.f,0.f,0.f}, h1a = {0.f,0.f,0.f,0.f};
        f32x4 x0a = {0.f,0.f,0.f,0.f}, x1a = {0.f,0.f,0.f,0.f};
#pragma unroll
        for (int kk = 0; kk < 16; ++kk) {
          const int aoff = ((kk * 64 + grp * 16) ^ ((lr & 7) << 4));
          short8 a = *(const short8*)(habuf + lr * 1024 + aoff);
          short8 ax = *(const short8*)(xabuf + lr * 1024 + aoff);
          if (kk & 1) {
            h1a = __builtin_amdgcn_mfma_f32_16x16x32_bf16(a, wfrag[kk], h1a, 0, 0, 0);
            x1a = __builtin_amdgcn_mfma_f32_16x16x32_bf16(ax, wfrag2[kk], x1a, 0, 0, 0);
          } else {
            h0a = __builtin_amdgcn_mfma_f32_16x16x32_bf16(a, wfrag[kk], h0a, 0, 0, 0);
            x0a = __builtin_amdgcn_mfma_f32_16x16x32_bf16(ax, wfrag2[kk], x0a, 0, 0, 0);
          }
        }
        f32x4 acc = (h0a + h1a) + (x0a + x1a);
        // in-register cell via butterfly; lane gt owns row grp*4+gt
        float hsel = 0.f; int hrow = 0, hv = 0;
#pragma unroll
        for (int q = 0; q < 4; ++q) {
          float v0f = acc[q] + bsum;
          float ex1 = __shfl_xor(v0f, 4);
          float a2 = (gt & 1) ? ex1 : v0f;
          float b2 = (gt & 1) ? v0f : ex1;
          float exA = __shfl_xor(a2, 8);
          float exB = __shfl_xor(b2, 8);
          float gi = (gt & 2) ? exA : a2;
          float gf = (gt & 2) ? exB : b2;
          float gg = (gt & 2) ? a2 : exA;
          float go = (gt & 2) ? b2 : exB;
          if (q == gt && vq[q]) {
            int i = i0 + grp * 4 + q;
            float cprev = CSEG[i * 32 + lcol];
            float cn = sigm(gf) * cprev + sigm(gi) * tanh_f(gg);
            CSEG[i * 32 + lcol] = cn;
            hsel = sigm(go) * tanh_f(cn);
            HST16[p * 512 + (grp * 4 + q) * 32 + lcol] = f2bf(hsel);
            hv = 1; hrow = rowq[q];
          }
        }
        __syncthreads();
        if (hv) y[(size_t)hrow * CDIM + cglob] = hsel;
        pend = p; pi0 = i0;
      }
      if (wv == 0 && pend >= 0)
        flush_tag(HST16, hexw, g, phw, pi0, Mn, pend, lane, cg, wtg);
      ++tg;  // next round's input tag
    }

    // chunk done: post flag so peers may reuse phase 0 for next chunk's seed
    ++fv;
    asm volatile("s_waitcnt vmcnt(0)" ::: "memory");
    __syncthreads();
    if (tid == 0)
      __hip_atomic_store(&flg[(g * 16 + cg) * 16], fv, __ATOMIC_RELAXED,
                         __HIP_MEMORY_SCOPE_AGENT);
  }
}

extern "C" void kernel_launch(void* const* d_in, const int* in_sizes, int n_in,
                              void* d_out, int out_size, void* d_ws, size_t ws_size,
                              hipStream_t stream) {
  (void)in_sizes; (void)n_in; (void)out_size;
  const float* x = (const float*)d_in[0];
  const void* rstp = (const void*)d_in[1];
  const float* h0 = (const float*)d_in[2];
  const float* c0 = (const float*)d_in[3];
  const float* wih = (const float*)d_in[4];
  const float* whh = (const float*)d_in[5];
  const float* bih = (const float*)d_in[6];
  const float* bhh = (const float*)d_in[7];
  float* y = (float*)d_out;

  if (ws_size < WS_NEED) return;  // diagnosable clean failure

  unsigned* hexw = (unsigned*)((char*)d_ws + HEXW_OFF);
  unsigned* GSEG = (unsigned*)((char*)d_ws + GSEG_OFF);
  unsigned* GCNT = (unsigned*)((char*)d_ws + GCNT_OFF);
  unsigned* flg = (unsigned*)((char*)d_ws + FLG_OFF);
  unsigned* SEGT = (unsigned*)((char*)d_ws + SEGT_OFF);

  // zero tags (tag 0 never used) + flags; ~32 MB, L3-speed
  (void)hipMemsetAsync(d_ws, 0, FLG_OFF + FLG_BYTES, stream);

  seg_setup<<<dim3(1), dim3(512), 0, stream>>>(rstp, GSEG, GCNT, SEGT);

  (void)hipFuncSetAttribute(reinterpret_cast<const void*>(rlstm_seq),
                            hipFuncAttributeMaxDynamicSharedMemorySize, SMEM_BYTES);
  void* args[] = {(void*)&x,    (void*)&h0,  (void*)&c0,   (void*)&whh,
                  (void*)&wih,  (void*)&bih, (void*)&bhh,  (void*)&y,
                  (void*)&hexw, (void*)&flg, (void*)&GSEG, (void*)&GCNT};
  (void)hipLaunchCooperativeKernel((void*)rlstm_seq, dim3(256), dim3(512), args,
                                   SMEM_BYTES, stream);
}

// Round 13
// 1428.436 us; speedup vs baseline: 6.2897x; 1.2713x over previous
//
#include <hip/hip_runtime.h>
#include <math.h>

typedef __attribute__((ext_vector_type(8))) short short8;
typedef __attribute__((ext_vector_type(4))) float f32x4;

#define TSTEPS 1024
#define BATCH  64
#define CDIM   512
#define CAP    256   // segments per group-chunk (ring-row capacity)
#define NPH    4     // ring phases

// ---- workspace layout ----
// HEXW: tagged u32 [16 groups][NPH][CAP rows][512 cols] = 32 MiB
#define HEXW_OFF   0
#define HEXW_BYTES ((size_t)16 * NPH * CAP * 512 * 4)
#define GSEG_OFF   (HEXW_OFF + HEXW_BYTES)
#define GSEG_BYTES ((size_t)65536 * 4)
#define GCNT_OFF   (GSEG_OFF + GSEG_BYTES)
#define GCNT_BYTES (1024 * 4)
#define FLG_OFF    (GCNT_OFF + GCNT_BYTES)
#define FLG_BYTES  (256 * 16 * 4)
#define SEGT_OFF   (FLG_OFF + FLG_BYTES)
#define SEGT_BYTES ((size_t)64 * 1024 * 4)
#define WS_NEED    (SEGT_OFF + SEGT_BYTES)

// ---- main kernel LDS map (dynamic, bytes) ----
// HA dbuf 2x16K @0 ; XA dbuf 2x16K @32768 ; CSEG f32[256][32] @65536 ;
// GC u32[1024] @98304 ; SEGL u32[256] @102400
#define SMEM_BYTES 103424   // > 81920 -> 1 block/CU

__device__ __forceinline__ unsigned short f2bf(float x) {
  unsigned u = __builtin_bit_cast(unsigned, x);
  unsigned r = (u + 0x7FFFu + ((u >> 16) & 1u)) >> 16;
  return (unsigned short)r;
}
__device__ __forceinline__ short8 pack8(float4 lo, float4 hi) {
  short8 r;
  r[0] = (short)f2bf(lo.x); r[1] = (short)f2bf(lo.y);
  r[2] = (short)f2bf(lo.z); r[3] = (short)f2bf(lo.w);
  r[4] = (short)f2bf(hi.x); r[5] = (short)f2bf(hi.y);
  r[6] = (short)f2bf(hi.z); r[7] = (short)f2bf(hi.w);
  return r;
}
__device__ __forceinline__ float sigm(float z) { return 1.0f / (1.0f + __expf(-z)); }
__device__ __forceinline__ float tanh_f(float x) {
  return 2.0f / (1.0f + __expf(-2.0f * x)) - 1.0f;
}

// chunk-boundary only: poll 15 peer flags
__device__ __forceinline__ void pollg(const unsigned* flg, int g, int cg,
                                      unsigned tgt, int lane) {
  const int idx = lane & 15;
  int rnd = 0;
  while (true) {
    unsigned v = (idx == cg)
                     ? 0xffffffffu
                     : __hip_atomic_load(&flg[(g * 16 + idx) * 16],
                                         __ATOMIC_RELAXED, __HIP_MEMORY_SCOPE_AGENT);
    if (__all((int)(v >= tgt))) break;
    if (rnd++) __builtin_amdgcn_s_sleep(1);
  }
  asm volatile("" ::: "memory");
}

// ============ kernel 0: segment extraction + counting sort by length desc ====
// GSEG[rank] packed: len(11)<<17 | start(10)<<7 | b(6)<<1 | seed(1).
// Rank p sorted by len desc; group g owns ranks p%16==g. GCNT[r] = #len>r.
__global__ __launch_bounds__(512) void seg_setup(const void* __restrict__ rst,
    unsigned* __restrict__ GSEG, unsigned* __restrict__ GCNT,
    unsigned* __restrict__ SEGT) {
  __shared__ unsigned long long RM[1024];
  __shared__ unsigned hist[1025], GCl[1025], cur[1025];
  __shared__ unsigned nsegb[64];
  __shared__ int s_oki, s_okf, s_oddnz;
  const int tid = threadIdx.x, lane = tid & 63, wv = tid >> 6;
  if (tid == 0) { s_oki = 1; s_okf = 1; s_oddnz = 0; }
  __syncthreads();
  {
    int oki = 1, okf = 1, oddnz = 0;
    for (int i = tid; i < 1024; i += 512) {
      unsigned v = ((const unsigned*)rst)[i];
      oki &= (v <= 1u);
      okf &= (v == 0u || v == 0x3F800000u);
      if ((i & 1) && v != 0u) oddnz = 1;
    }
    if (!oki) atomicAnd(&s_oki, 0);
    if (!okf) atomicAnd(&s_okf, 0);
    if (oddnz) atomicOr(&s_oddnz, 1);
  }
  __syncthreads();
  const int mode = s_oki ? (s_oddnz ? 0 : 3) : (s_okf ? 2 : 1);
  for (int tt = wv; tt < 1024; tt += 8) {
    int idx = tt * BATCH + lane;
    bool r;
    if (mode == 0)      r = ((const int*)rst)[idx] != 0;
    else if (mode == 1) r = ((const unsigned char*)rst)[idx] != 0;
    else if (mode == 2) r = ((const float*)rst)[idx] != 0.0f;
    else                r = ((const int*)rst)[2 * idx] != 0;
    unsigned long long bm = __ballot((int)r);
    if (lane == 0) RM[tt] = bm;
  }
  for (int i = tid; i < 1025; i += 512) { hist[i] = 0; cur[i] = 0; }
  __syncthreads();
  if (tid < 64) {
    int b = tid; unsigned cnt = 0; int s = 0;
    unsigned seed0 = ((RM[0] >> b) & 1ull) ? 0u : 1u;
    for (int t = 1; t < 1024; ++t) {
      if ((RM[t] >> b) & 1ull) {
        unsigned len = (unsigned)(t - s);
        unsigned sd = (s == 0) ? seed0 : 0u;
        SEGT[b * 1024 + cnt++] = (len << 17) | ((unsigned)s << 7) | ((unsigned)b << 1) | sd;
        atomicAdd(&hist[len], 1u);
        s = t;
      }
    }
    { unsigned len = (unsigned)(1024 - s);
      unsigned sd = (s == 0) ? seed0 : 0u;
      SEGT[b * 1024 + cnt++] = (len << 17) | ((unsigned)s << 7) | ((unsigned)b << 1) | sd;
      atomicAdd(&hist[len], 1u); }
    nsegb[b] = cnt;
  }
  __syncthreads();
  if (tid == 0) {
    unsigned acc = 0;
    for (int r = 1023; r >= 0; --r) { acc += hist[r + 1]; GCl[r] = acc; }
    GCl[1024] = 0;
  }
  __syncthreads();
  if (tid < 64) {
    int b = tid;
    for (unsigned k = 0; k < nsegb[b]; ++k) {
      unsigned v = SEGT[b * 1024 + k];
      unsigned len = v >> 17;
      unsigned p = GCl[len] + atomicAdd(&cur[len], 1u);
      GSEG[p] = v;
    }
  }
  __syncthreads();
  for (int i = tid; i < 1024; i += 512) GCNT[i] = GCl[i];
}

// ============ kernel 1: depth-parallel LSTM, tagged 4-phase ring exchange ====
// Per tile: stage x + poll/stage h -> ONE barrier -> 32 MFMA -> 4-shfl gate
// transpose -> full-wave cell -> per-lane tagged flush (no LDS, no 2nd barrier).
__global__ __launch_bounds__(512, 1) void rlstm_seq(
    const float* __restrict__ x, const float* __restrict__ h0,
    const float* __restrict__ c0, const float* __restrict__ whh,
    const float* __restrict__ wih, const float* __restrict__ bih,
    const float* __restrict__ bhh, float* __restrict__ y,
    unsigned* __restrict__ hexw, unsigned* __restrict__ flg,
    const unsigned* __restrict__ GSEG, const unsigned* __restrict__ GCNT) {
  extern __shared__ __align__(16) char smem[];
  float* CSEG = (float*)(smem + 65536);
  unsigned* GC = (unsigned*)(smem + 98304);
  unsigned* SEGL = (unsigned*)(smem + 102400);

  const int tid = threadIdx.x, bid = blockIdx.x;
  const int g = bid >> 4, cg = bid & 15;
  const int lane = tid & 63, wv = tid >> 6;
  const int grp = lane >> 4, lr = lane & 15;
  const int gt = lr >> 2, j = lr & 3;
  const int lcol = wv * 4 + j;
  const int cglob = cg * 32 + lcol;
  const int nglob = gt * CDIM + cglob;
  const int srow = 2 * wv + (lane >> 5);
  const int wcol = lane & 31;
  const int swz = (srow & 7) << 4;

  // both weight slices register-resident: 128 VGPR/wave
  short8 wfrag[16], wfrag2[16];
#pragma unroll
  for (int kk = 0; kk < 16; ++kk) {
    const float* s = whh + (size_t)nglob * CDIM + kk * 32 + grp * 8;
    float4 lo = *(const float4*)s, hi = *(const float4*)(s + 4);
    wfrag[kk] = pack8(lo, hi);
    const float* s2 = wih + (size_t)nglob * CDIM + kk * 32 + grp * 8;
    float4 lo2 = *(const float4*)s2, hi2 = *(const float4*)(s2 + 4);
    wfrag2[kk] = pack8(lo2, hi2);
  }
  const float bsum = bih[nglob] + bhh[nglob];

  for (int i = tid; i < 1024; i += 512) GC[i] = GCNT[i];
  __syncthreads();

  const unsigned G0 = GC[0];
  const unsigned totg = (G0 > (unsigned)g) ? ((G0 - g + 15u) >> 4) : 0u;
  const int nchunks = (int)((totg + CAP - 1) / CAP);
  unsigned tg = 0, fv = 0;

  for (int chunk = 0; chunk < nchunks; ++chunk) {
    const unsigned cb = (unsigned)chunk * CAP;
    int M0;
    { unsigned t2 = totg;
      M0 = (t2 > cb) ? (int)((t2 - cb > CAP) ? CAP : (t2 - cb)) : 0; }
    if (M0 == 0) break;
    if (chunk > 0) pollg(flg, g, cg, fv, lane);  // peers exited prior chunk

    ++tg;  // seed tag (consumed by round 0)
    // ---- seed phase 0 + CSEG + SEGL ----
    for (int i = tid >> 4; i < M0; i += 32) {
      int c2 = (tid & 15) * 2;
      unsigned sv = GSEG[(size_t)(cb + i) * 16 + g];
      if ((tid & 15) == 0) SEGL[i] = sv;
      int b = (sv >> 1) & 63;
      float ha = 0.f, hb = 0.f, ca = 0.f, cbv = 0.f;
      if (sv & 1u) {
        const float* hp = h0 + (size_t)b * CDIM + cg * 32 + c2;
        ha = hp[0]; hb = hp[1];
        const float* cp = c0 + (size_t)b * CDIM + cg * 32 + c2;
        ca = cp[0]; cbv = cp[1];
      }
      CSEG[i * 32 + c2] = ca; CSEG[i * 32 + c2 + 1] = cbv;
      unsigned lo = ((unsigned)f2bf(ha) << 16) | tg;
      unsigned hi2 = ((unsigned)f2bf(hb) << 16) | tg;
      unsigned long long w = ((unsigned long long)hi2 << 32) | lo;
      __hip_atomic_store((unsigned long long*)hexw +
                             ((size_t)(g * NPH + 0) * CAP + i) * 256 + cg * 16 +
                             (tid & 15),
                         w, __ATOMIC_RELAXED, __HIP_MEMORY_SCOPE_AGENT);
    }
    __syncthreads();  // SEGL/CSEG ready

    // ---- depth rounds ----
    for (int r = 0;; ++r) {
      if (r >= 1024) break;
      int M;
      { unsigned Gr = GC[r];
        unsigned t2 = (Gr > (unsigned)g) ? ((Gr - g + 15u) >> 4) : 0u;
        M = (t2 > cb) ? (int)((t2 - cb > CAP) ? CAP : (t2 - cb)) : 0; }
      if (M == 0) break;
      int Mn = 0;
      if (r + 1 < 1024) {
        unsigned Gn = GC[r + 1];
        unsigned t2 = (Gn > (unsigned)g) ? ((Gn - g + 15u) >> 4) : 0u;
        Mn = (t2 > cb) ? (int)((t2 - cb > CAP) ? CAP : (t2 - cb)) : 0;
      }
      const int ph = r & (NPH - 1), phw = (r + 1) & (NPH - 1);
      const unsigned wtg = tg + 1;
      unsigned* const wbase = hexw + (size_t)(g * NPH + phw) * CAP * 512;

      for (int i0 = 0; i0 < M; i0 += 16) {
        const int p = ((i0 >> 4) + r) & 1;
        // stage x rows for this tile into XA[p] (L3-resident gather)
        { int i = i0 + srow;
          if (i < M) {
            unsigned sv = SEGL[i];
            int b = (sv >> 1) & 63, s0 = (sv >> 7) & 1023;
            const float* xr = x + ((size_t)(s0 + r) * BATCH + b) * CDIM;
            char* xabuf = smem + 32768 + p * 16384;
#pragma unroll
            for (int k2 = 0; k2 < 2; ++k2) {
              int pp = wcol + 32 * k2;
              float4 lo = *(const float4*)(xr + pp * 8);
              float4 hi = *(const float4*)(xr + pp * 8 + 4);
              *(short8*)(xabuf + srow * 1024 + ((pp * 16) ^ swz)) = pack8(lo, hi);
            }
          }
        }
        // poll + stage h_prev tile (tagged words ARE the handshake)
        char* habuf = smem + p * 16384;
        { int i = i0 + srow;
          if (i < M) {
            const unsigned long long* hq = (const unsigned long long*)hexw +
                ((size_t)(g * NPH + ph) * CAP + i) * 256;
            unsigned long long v8[8];
            unsigned pn = 0xffu;
            int rnd = 0;
            do {
              if (rnd++) __builtin_amdgcn_s_sleep(1);
#pragma unroll
              for (int k = 0; k < 8; ++k)
                if (pn & (1u << k))
                  v8[k] = __hip_atomic_load(hq + wcol + 32 * k, __ATOMIC_RELAXED,
                                            __HIP_MEMORY_SCOPE_AGENT);
              unsigned np = 0;
#pragma unroll
              for (int k = 0; k < 8; ++k) {
                unsigned lo = (unsigned)v8[k];
                unsigned hi = (unsigned)(v8[k] >> 32);
                if (((lo ^ tg) | (hi ^ tg)) & 0xffffu) np |= 1u << k;
              }
              pn = np;
            } while (__any((int)pn));
#pragma unroll
            for (int k = 0; k < 8; ++k) {
              unsigned lo = (unsigned)v8[k];
              unsigned hi = (unsigned)(v8[k] >> 32);
              unsigned pk = (lo >> 16) | (hi & 0xffff0000u);
              int m = wcol + 32 * k;
              *(unsigned*)(habuf + srow * 1024 + ((m * 4) ^ swz)) = pk;
            }
          }
        }
        __syncthreads();  // the ONLY barrier per tile

        // recurrent + input GEMMs: dual chains each
        char* xabuf = smem + 32768 + p * 16384;
        f32x4 h0a = {0.f,0.f,0.f,0.f}, h1a = {0.f,0.f,0.f,0.f};
        f32x4 x0a = {0.f,0.f,0.f,0.f}, x1a = {0.f,0.f,0.f,0.f};
#pragma unroll
        for (int kk = 0; kk < 16; ++kk) {
          const int aoff = ((kk * 64 + grp * 16) ^ ((lr & 7) << 4));
          short8 a = *(const short8*)(habuf + lr * 1024 + aoff);
          short8 ax = *(const short8*)(xabuf + lr * 1024 + aoff);
          if (kk & 1) {
            h1a = __builtin_amdgcn_mfma_f32_16x16x32_bf16(a, wfrag[kk], h1a, 0, 0, 0);
            x1a = __builtin_amdgcn_mfma_f32_16x16x32_bf16(ax, wfrag2[kk], x1a, 0, 0, 0);
          } else {
            h0a = __builtin_amdgcn_mfma_f32_16x16x32_bf16(a, wfrag[kk], h0a, 0, 0, 0);
            x0a = __builtin_amdgcn_mfma_f32_16x16x32_bf16(ax, wfrag2[kk], x0a, 0, 0, 0);
          }
        }
        f32x4 acc = (h0a + h1a) + (x0a + x1a);

        // ---- 4x4 gate transpose across gt-lanes (4 shfl), then one cell ----
        float a0 = acc[0] + bsum, a1 = acc[1] + bsum;
        float a2 = acc[2] + bsum, a3 = acc[3] + bsum;
        const int b0 = gt & 1, b1 = (gt >> 1) & 1;
        float sA0 = b0 ? a0 : a1;           // a[b0^1]
        float sA1 = b0 ? a2 : a3;           // a[(b0^1)+2]
        float rA0 = __shfl_xor(sA0, 4);     // partner's a[b0]
        float rA1 = __shfl_xor(sA1, 4);     // partner's a[b0+2]
        float k0 = b0 ? a1 : a0;            // a[b0]
        float k1 = b0 ? a3 : a2;            // a[b0+2]
        float sB0 = b1 ? k0 : k1;
        float sB1 = b1 ? rA0 : rA1;
        float rB0 = __shfl_xor(sB0, 8);     // gate gt^2
        float rB1 = __shfl_xor(sB1, 8);     // gate gt^3
        float m0 = b1 ? k1 : k0;            // gate gt
        float m1 = b1 ? rA1 : rA0;          // gate gt^1
        float gi = (gt == 0) ? m0 : (gt == 1) ? m1 : (gt == 2) ? rB0 : rB1;
        float gf = (gt == 1) ? m0 : (gt == 0) ? m1 : (gt == 3) ? rB0 : rB1;
        float gg = (gt == 2) ? m0 : (gt == 3) ? m1 : (gt == 0) ? rB0 : rB1;
        float go = (gt == 3) ? m0 : (gt == 2) ? m1 : (gt == 1) ? rB0 : rB1;

        const int i = i0 + grp * 4 + gt;    // this lane's row
        if (i < M) {
          float cprev = CSEG[i * 32 + lcol];
          float cn = sigm(gf) * cprev + sigm(gi) * tanh_f(gg);
          CSEG[i * 32 + lcol] = cn;
          float hsel = sigm(go) * tanh_f(cn);
          if (i < Mn) {
            unsigned w = ((unsigned)f2bf(hsel) << 16) | wtg;
            __hip_atomic_store(wbase + (size_t)i * 512 + cglob, w,
                               __ATOMIC_RELAXED, __HIP_MEMORY_SCOPE_AGENT);
          }
          unsigned sv = SEGL[i];
          int rowm = (int)((((sv >> 7) & 1023) + r) * BATCH + ((sv >> 1) & 63));
          y[(size_t)rowm * CDIM + cglob] = hsel;
        }
      }
      ++tg;  // next round's input tag
    }

    // chunk done: post flag so peers may reuse phase 0 for next chunk's seed
    ++fv;
    asm volatile("s_waitcnt vmcnt(0)" ::: "memory");
    __syncthreads();
    if (tid == 0)
      __hip_atomic_store(&flg[(g * 16 + cg) * 16], fv, __ATOMIC_RELAXED,
                         __HIP_MEMORY_SCOPE_AGENT);
  }
}

extern "C" void kernel_launch(void* const* d_in, const int* in_sizes, int n_in,
                              void* d_out, int out_size, void* d_ws, size_t ws_size,
                              hipStream_t stream) {
  (void)in_sizes; (void)n_in; (void)out_size;
  const float* x = (const float*)d_in[0];
  const void* rstp = (const void*)d_in[1];
  const float* h0 = (const float*)d_in[2];
  const float* c0 = (const float*)d_in[3];
  const float* wih = (const float*)d_in[4];
  const float* whh = (const float*)d_in[5];
  const float* bih = (const float*)d_in[6];
  const float* bhh = (const float*)d_in[7];
  float* y = (float*)d_out;

  if (ws_size < WS_NEED) return;  // diagnosable clean failure

  unsigned* hexw = (unsigned*)((char*)d_ws + HEXW_OFF);
  unsigned* GSEG = (unsigned*)((char*)d_ws + GSEG_OFF);
  unsigned* GCNT = (unsigned*)((char*)d_ws + GCNT_OFF);
  unsigned* flg = (unsigned*)((char*)d_ws + FLG_OFF);
  unsigned* SEGT = (unsigned*)((char*)d_ws + SEGT_OFF);

  // zero tags (tag 0 never used) + flags; ~32 MB, L3-speed
  (void)hipMemsetAsync(d_ws, 0, FLG_OFF + FLG_BYTES, stream);

  seg_setup<<<dim3(1), dim3(512), 0, stream>>>(rstp, GSEG, GCNT, SEGT);

  (void)hipFuncSetAttribute(reinterpret_cast<const void*>(rlstm_seq),
                            hipFuncAttributeMaxDynamicSharedMemorySize, SMEM_BYTES);
  void* args[] = {(void*)&x,    (void*)&h0,  (void*)&c0,   (void*)&whh,
                  (void*)&wih,  (void*)&bih, (void*)&bhh,  (void*)&y,
                  (void*)&hexw, (void*)&flg, (void*)&GSEG, (void*)&GCNT};
  (void)hipLaunchCooperativeKernel((void*)rlstm_seq, dim3(256), dim3(512), args,
                                   SMEM_BYTES, stream);
}

// Round 14
// 1361.951 us; speedup vs baseline: 6.5967x; 1.0488x over previous
//
#include <hip/hip_runtime.h>
#include <math.h>

typedef __attribute__((ext_vector_type(8))) short short8;
typedef __attribute__((ext_vector_type(4))) float f32x4;

#define TSTEPS 1024
#define BATCH  64
#define CDIM   512
#define CAP    256   // segments per group-chunk (ring-row capacity)
#define NPH    4     // ring phases

// ---- workspace layout ----
// HEXW: tagged u32 [16 groups][NPH][CAP rows][512 cols] = 32 MiB
#define HEXW_OFF   0
#define HEXW_BYTES ((size_t)16 * NPH * CAP * 512 * 4)
#define GSEG_OFF   (HEXW_OFF + HEXW_BYTES)
#define GSEG_BYTES ((size_t)65536 * 4)
#define GCNT_OFF   (GSEG_OFF + GSEG_BYTES)
#define GCNT_BYTES (1024 * 4)
#define FLG_OFF    (GCNT_OFF + GCNT_BYTES)
#define FLG_BYTES  (256 * 16 * 4)
#define SEGT_OFF   (FLG_OFF + FLG_BYTES)
#define SEGT_BYTES ((size_t)64 * 1024 * 4)
#define WS_NEED    (SEGT_OFF + SEGT_BYTES)

// ---- main kernel LDS map (dynamic, bytes) ----
// HA dbuf 2x16K @0 ; XA dbuf 2x16K @32768 ; CSEG f32[256][32] @65536 ;
// GC u32[1024] @98304 ; SEGL u32[256] @102400
#define SMEM_BYTES 103424   // > 81920 -> 1 block/CU

__device__ __forceinline__ unsigned short f2bf(float x) {
  unsigned u = __builtin_bit_cast(unsigned, x);
  unsigned r = (u + 0x7FFFu + ((u >> 16) & 1u)) >> 16;
  return (unsigned short)r;
}
__device__ __forceinline__ short8 pack8(float4 lo, float4 hi) {
  short8 r;
  r[0] = (short)f2bf(lo.x); r[1] = (short)f2bf(lo.y);
  r[2] = (short)f2bf(lo.z); r[3] = (short)f2bf(lo.w);
  r[4] = (short)f2bf(hi.x); r[5] = (short)f2bf(hi.y);
  r[6] = (short)f2bf(hi.z); r[7] = (short)f2bf(hi.w);
  return r;
}
__device__ __forceinline__ float sigm(float z) { return 1.0f / (1.0f + __expf(-z)); }
__device__ __forceinline__ float tanh_f(float x) {
  return 2.0f / (1.0f + __expf(-2.0f * x)) - 1.0f;
}
// exponential backoff: 0, 64, 128, 256, 512+ cycles
__device__ __forceinline__ void backoff(int rnd) {
  if (rnd == 1) __builtin_amdgcn_s_sleep(1);
  else if (rnd == 2) __builtin_amdgcn_s_sleep(2);
  else if (rnd == 3) __builtin_amdgcn_s_sleep(4);
  else if (rnd >= 4) __builtin_amdgcn_s_sleep(8);
}

// chunk-boundary only: poll 15 peer flags
__device__ __forceinline__ void pollg(const unsigned* flg, int g, int cg,
                                      unsigned tgt, int lane) {
  const int idx = lane & 15;
  int rnd = 0;
  while (true) {
    unsigned v = (idx == cg)
                     ? 0xffffffffu
                     : __hip_atomic_load(&flg[(g * 16 + idx) * 16],
                                         __ATOMIC_RELAXED, __HIP_MEMORY_SCOPE_AGENT);
    if (__all((int)(v >= tgt))) break;
    backoff(++rnd > 8 ? 8 : rnd);
  }
  asm volatile("" ::: "memory");
}

// ============ kernel 0: segment extraction + counting sort by length desc ====
// GSEG[rank] packed: len(11)<<17 | start(10)<<7 | b(6)<<1 | seed(1).
// Rank p sorted by len desc; group g owns ranks p%16==g. GCNT[r] = #len>r.
// Fast path: ballot-transpose reset mask to per-b u64 words, ctz extraction.
__global__ __launch_bounds__(512) void seg_setup(const void* __restrict__ rst,
    unsigned* __restrict__ GSEG, unsigned* __restrict__ GCNT,
    unsigned* __restrict__ SEGT) {
  __shared__ unsigned long long RM[1024];     // per-t batch mask
  __shared__ unsigned long long BM[64][17];   // per-b time mask (16 u64 + pad)
  __shared__ unsigned hist[1025], GCl[1025], cur[1025];
  __shared__ unsigned nsegb[64];
  __shared__ int s_oki, s_okf, s_oddnz;
  const int tid = threadIdx.x, lane = tid & 63, wv = tid >> 6;
  if (tid == 0) { s_oki = 1; s_okf = 1; s_oddnz = 0; }
  __syncthreads();
  {
    int oki = 1, okf = 1, oddnz = 0;
    for (int i = tid; i < 1024; i += 512) {
      unsigned v = ((const unsigned*)rst)[i];
      oki &= (v <= 1u);
      okf &= (v == 0u || v == 0x3F800000u);
      if ((i & 1) && v != 0u) oddnz = 1;
    }
    if (!oki) atomicAnd(&s_oki, 0);
    if (!okf) atomicAnd(&s_okf, 0);
    if (oddnz) atomicOr(&s_oddnz, 1);
  }
  __syncthreads();
  const int mode = s_oki ? (s_oddnz ? 0 : 3) : (s_okf ? 2 : 1);
  for (int tt = wv; tt < 1024; tt += 8) {
    int idx = tt * BATCH + lane;
    bool r;
    if (mode == 0)      r = ((const int*)rst)[idx] != 0;
    else if (mode == 1) r = ((const unsigned char*)rst)[idx] != 0;
    else if (mode == 2) r = ((const float*)rst)[idx] != 0.0f;
    else                r = ((const int*)rst)[2 * idx] != 0;
    unsigned long long bm = __ballot((int)r);
    if (lane == 0) RM[tt] = bm;
  }
  for (int i = tid; i < 1025; i += 512) { hist[i] = 0; cur[i] = 0; }
  __syncthreads();
  // ballot transpose: BM[b][w] bit t' = reset[w*64+t'][b]
  for (int idx = wv; idx < 1024; idx += 8) {
    int b = idx >> 4, w = idx & 15;
    unsigned long long bit = (RM[w * 64 + lane] >> b) & 1ull;
    unsigned long long m = __ballot((int)(bit != 0ull));
    if (lane == 0) BM[b][w] = m;
  }
  __syncthreads();
  if (tid < 64) {
    int b = tid; unsigned cnt = 0; int s = 0;
    unsigned seed0 = (BM[b][0] & 1ull) ? 0u : 1u;
    for (int w = 0; w < 16; ++w) {
      unsigned long long m = BM[b][w];
      if (w == 0) m &= ~1ull;  // t=0 reset handled via seed bit, not a boundary
      while (m) {
        int t = w * 64 + __builtin_ctzll(m);
        m &= m - 1;
        unsigned len = (unsigned)(t - s);
        unsigned sd = (s == 0) ? seed0 : 0u;
        SEGT[b * 1024 + cnt++] =
            (len << 17) | ((unsigned)s << 7) | ((unsigned)b << 1) | sd;
        atomicAdd(&hist[len], 1u);
        s = t;
      }
    }
    { unsigned len = (unsigned)(1024 - s);
      unsigned sd = (s == 0) ? seed0 : 0u;
      SEGT[b * 1024 + cnt++] =
          (len << 17) | ((unsigned)s << 7) | ((unsigned)b << 1) | sd;
      atomicAdd(&hist[len], 1u); }
    nsegb[b] = cnt;
  }
  __syncthreads();
  if (tid == 0) {
    unsigned acc = 0;
    for (int r = 1023; r >= 0; --r) { acc += hist[r + 1]; GCl[r] = acc; }
    GCl[1024] = 0;
  }
  __syncthreads();
  if (tid < 64) {
    int b = tid;
    for (unsigned k = 0; k < nsegb[b]; ++k) {
      unsigned v = SEGT[b * 1024 + k];
      unsigned len = v >> 17;
      unsigned p = GCl[len] + atomicAdd(&cur[len], 1u);
      GSEG[p] = v;
    }
  }
  __syncthreads();
  for (int i = tid; i < 1024; i += 512) GCNT[i] = GCl[i];
}

// ============ kernel 1: depth-parallel LSTM, tagged 4-phase ring exchange ====
// Per tile: stage x + poll/stage h -> ONE barrier -> 32 MFMA -> 4-shfl gate
// transpose -> full-wave cell -> per-lane tagged flush (no LDS, no 2nd barrier).
__global__ __launch_bounds__(512, 1) void rlstm_seq(
    const float* __restrict__ x, const float* __restrict__ h0,
    const float* __restrict__ c0, const float* __restrict__ whh,
    const float* __restrict__ wih, const float* __restrict__ bih,
    const float* __restrict__ bhh, float* __restrict__ y,
    unsigned* __restrict__ hexw, unsigned* __restrict__ flg,
    const unsigned* __restrict__ GSEG, const unsigned* __restrict__ GCNT) {
  extern __shared__ __align__(16) char smem[];
  float* CSEG = (float*)(smem + 65536);
  unsigned* GC = (unsigned*)(smem + 98304);
  unsigned* SEGL = (unsigned*)(smem + 102400);

  const int tid = threadIdx.x, bid = blockIdx.x;
  const int g = bid >> 4, cg = bid & 15;
  const int lane = tid & 63, wv = tid >> 6;
  const int grp = lane >> 4, lr = lane & 15;
  const int gt = lr >> 2, j = lr & 3;
  const int lcol = wv * 4 + j;
  const int cglob = cg * 32 + lcol;
  const int nglob = gt * CDIM + cglob;
  const int srow = 2 * wv + (lane >> 5);
  const int wcol = lane & 31;
  const int swz = (srow & 7) << 4;

  // both weight slices register-resident: 128 VGPR/wave
  short8 wfrag[16], wfrag2[16];
#pragma unroll
  for (int kk = 0; kk < 16; ++kk) {
    const float* s = whh + (size_t)nglob * CDIM + kk * 32 + grp * 8;
    float4 lo = *(const float4*)s, hi = *(const float4*)(s + 4);
    wfrag[kk] = pack8(lo, hi);
    const float* s2 = wih + (size_t)nglob * CDIM + kk * 32 + grp * 8;
    float4 lo2 = *(const float4*)s2, hi2 = *(const float4*)(s2 + 4);
    wfrag2[kk] = pack8(lo2, hi2);
  }
  const float bsum = bih[nglob] + bhh[nglob];

  for (int i = tid; i < 1024; i += 512) GC[i] = GCNT[i];
  __syncthreads();

  const unsigned G0 = GC[0];
  const unsigned totg = (G0 > (unsigned)g) ? ((G0 - g + 15u) >> 4) : 0u;
  const int nchunks = (int)((totg + CAP - 1) / CAP);
  unsigned tg = 0, fv = 0;

  for (int chunk = 0; chunk < nchunks; ++chunk) {
    const unsigned cb = (unsigned)chunk * CAP;
    int M0;
    { unsigned t2 = totg;
      M0 = (t2 > cb) ? (int)((t2 - cb > CAP) ? CAP : (t2 - cb)) : 0; }
    if (M0 == 0) break;
    if (chunk > 0) pollg(flg, g, cg, fv, lane);  // peers exited prior chunk

    ++tg;  // seed tag (consumed by round 0)
    // ---- seed phase 0 + CSEG + SEGL ----
    for (int i = tid >> 4; i < M0; i += 32) {
      int c2 = (tid & 15) * 2;
      unsigned sv = GSEG[(size_t)(cb + i) * 16 + g];
      if ((tid & 15) == 0) SEGL[i] = sv;
      int b = (sv >> 1) & 63;
      float ha = 0.f, hb = 0.f, ca = 0.f, cbv = 0.f;
      if (sv & 1u) {
        const float* hp = h0 + (size_t)b * CDIM + cg * 32 + c2;
        ha = hp[0]; hb = hp[1];
        const float* cp = c0 + (size_t)b * CDIM + cg * 32 + c2;
        ca = cp[0]; cbv = cp[1];
      }
      CSEG[i * 32 + c2] = ca; CSEG[i * 32 + c2 + 1] = cbv;
      unsigned lo = ((unsigned)f2bf(ha) << 16) | tg;
      unsigned hi2 = ((unsigned)f2bf(hb) << 16) | tg;
      unsigned long long w = ((unsigned long long)hi2 << 32) | lo;
      __hip_atomic_store((unsigned long long*)hexw +
                             ((size_t)(g * NPH + 0) * CAP + i) * 256 + cg * 16 +
                             (tid & 15),
                         w, __ATOMIC_RELAXED, __HIP_MEMORY_SCOPE_AGENT);
    }
    __syncthreads();  // SEGL/CSEG ready

    // ---- depth rounds ----
    for (int r = 0;; ++r) {
      if (r >= 1024) break;
      int M;
      { unsigned Gr = GC[r];
        unsigned t2 = (Gr > (unsigned)g) ? ((Gr - g + 15u) >> 4) : 0u;
        M = (t2 > cb) ? (int)((t2 - cb > CAP) ? CAP : (t2 - cb)) : 0; }
      if (M == 0) break;
      int Mn = 0;
      if (r + 1 < 1024) {
        unsigned Gn = GC[r + 1];
        unsigned t2 = (Gn > (unsigned)g) ? ((Gn - g + 15u) >> 4) : 0u;
        Mn = (t2 > cb) ? (int)((t2 - cb > CAP) ? CAP : (t2 - cb)) : 0;
      }
      const int ph = r & (NPH - 1), phw = (r + 1) & (NPH - 1);
      const unsigned wtg = tg + 1;
      unsigned* const wbase = hexw + (size_t)(g * NPH + phw) * CAP * 512;

      for (int i0 = 0; i0 < M; i0 += 16) {
        const int p = ((i0 >> 4) + r) & 1;
        // stage x rows for this tile into XA[p] (L3-resident gather)
        { int i = i0 + srow;
          if (i < M) {
            unsigned sv = SEGL[i];
            int b = (sv >> 1) & 63, s0 = (sv >> 7) & 1023;
            const float* xr = x + ((size_t)(s0 + r) * BATCH + b) * CDIM;
            char* xabuf = smem + 32768 + p * 16384;
#pragma unroll
            for (int k2 = 0; k2 < 2; ++k2) {
              int pp = wcol + 32 * k2;
              float4 lo = *(const float4*)(xr + pp * 8);
              float4 hi = *(const float4*)(xr + pp * 8 + 4);
              *(short8*)(xabuf + srow * 1024 + ((pp * 16) ^ swz)) = pack8(lo, hi);
            }
          }
        }
        // poll + stage h_prev tile (tagged words ARE the handshake)
        char* habuf = smem + p * 16384;
        { int i = i0 + srow;
          if (i < M) {
            const unsigned long long* hq = (const unsigned long long*)hexw +
                ((size_t)(g * NPH + ph) * CAP + i) * 256;
            unsigned long long v8[8];
            unsigned pn = 0xffu;
            int rnd = 0;
            do {
              backoff(rnd > 4 ? 4 : rnd);
              ++rnd;
#pragma unroll
              for (int k = 0; k < 8; ++k)
                if (pn & (1u << k))
                  v8[k] = __hip_atomic_load(hq + wcol + 32 * k, __ATOMIC_RELAXED,
                                            __HIP_MEMORY_SCOPE_AGENT);
              unsigned np = 0;
#pragma unroll
              for (int k = 0; k < 8; ++k) {
                unsigned lo = (unsigned)v8[k];
                unsigned hi = (unsigned)(v8[k] >> 32);
                if (((lo ^ tg) | (hi ^ tg)) & 0xffffu) np |= 1u << k;
              }
              pn = np;
            } while (__any((int)pn));
#pragma unroll
            for (int k = 0; k < 8; ++k) {
              unsigned lo = (unsigned)v8[k];
              unsigned hi = (unsigned)(v8[k] >> 32);
              unsigned pk = (lo >> 16) | (hi & 0xffff0000u);
              int m = wcol + 32 * k;
              *(unsigned*)(habuf + srow * 1024 + ((m * 4) ^ swz)) = pk;
            }
          }
        }
        __syncthreads();  // the ONLY barrier per tile

        // recurrent + input GEMMs: dual chains each
        char* xabuf = smem + 32768 + p * 16384;
        f32x4 h0a = {0.f,0.f,0.f,0.f}, h1a = {0.f,0.f,0.f,0.f};
        f32x4 x0a = {0.f,0.f,0.f,0.f}, x1a = {0.f,0.f,0.f,0.f};
#pragma unroll
        for (int kk = 0; kk < 16; ++kk) {
          const int aoff = ((kk * 64 + grp * 16) ^ ((lr & 7) << 4));
          short8 a = *(const short8*)(habuf + lr * 1024 + aoff);
          short8 ax = *(const short8*)(xabuf + lr * 1024 + aoff);
          if (kk & 1) {
            h1a = __builtin_amdgcn_mfma_f32_16x16x32_bf16(a, wfrag[kk], h1a, 0, 0, 0);
            x1a = __builtin_amdgcn_mfma_f32_16x16x32_bf16(ax, wfrag2[kk], x1a, 0, 0, 0);
          } else {
            h0a = __builtin_amdgcn_mfma_f32_16x16x32_bf16(a, wfrag[kk], h0a, 0, 0, 0);
            x0a = __builtin_amdgcn_mfma_f32_16x16x32_bf16(ax, wfrag2[kk], x0a, 0, 0, 0);
          }
        }
        f32x4 acc = (h0a + h1a) + (x0a + x1a);

        // ---- 4x4 gate transpose across gt-lanes (4 shfl), then one cell ----
        float a0 = acc[0] + bsum, a1 = acc[1] + bsum;
        float a2 = acc[2] + bsum, a3 = acc[3] + bsum;
        const int b0 = gt & 1, b1 = (gt >> 1) & 1;
        float sA0 = b0 ? a0 : a1;           // a[b0^1]
        float sA1 = b0 ? a2 : a3;           // a[(b0^1)+2]
        float rA0 = __shfl_xor(sA0, 4);     // partner's a[b0]
        float rA1 = __shfl_xor(sA1, 4);     // partner's a[b0+2]
        float k0 = b0 ? a1 : a0;            // a[b0]
        float k1 = b0 ? a3 : a2;            // a[b0+2]
        float sB0 = b1 ? k0 : k1;
        float sB1 = b1 ? rA0 : rA1;
        float rB0 = __shfl_xor(sB0, 8);     // gate gt^2
        float rB1 = __shfl_xor(sB1, 8);     // gate gt^3
        float m0 = b1 ? k1 : k0;            // gate gt
        float m1 = b1 ? rA1 : rA0;          // gate gt^1
        float gi = (gt == 0) ? m0 : (gt == 1) ? m1 : (gt == 2) ? rB0 : rB1;
        float gf = (gt == 1) ? m0 : (gt == 0) ? m1 : (gt == 3) ? rB0 : rB1;
        float gg = (gt == 2) ? m0 : (gt == 3) ? m1 : (gt == 0) ? rB0 : rB1;
        float go = (gt == 3) ? m0 : (gt == 2) ? m1 : (gt == 1) ? rB0 : rB1;

        const int i = i0 + grp * 4 + gt;    // this lane's row
        if (i < M) {
          float cprev = CSEG[i * 32 + lcol];
          float cn = sigm(gf) * cprev + sigm(gi) * tanh_f(gg);
          CSEG[i * 32 + lcol] = cn;
          float hsel = sigm(go) * tanh_f(cn);
          if (i < Mn) {
            unsigned w = ((unsigned)f2bf(hsel) << 16) | wtg;
            __hip_atomic_store(wbase + (size_t)i * 512 + cglob, w,
                               __ATOMIC_RELAXED, __HIP_MEMORY_SCOPE_AGENT);
          }
          unsigned sv = SEGL[i];
          int rowm = (int)((((sv >> 7) & 1023) + r) * BATCH + ((sv >> 1) & 63));
          y[(size_t)rowm * CDIM + cglob] = hsel;
        }
      }
      ++tg;  // next round's input tag
    }

    // chunk done: post flag so peers may reuse phase 0 for next chunk's seed
    ++fv;
    asm volatile("s_waitcnt vmcnt(0)" ::: "memory");
    __syncthreads();
    if (tid == 0)
      __hip_atomic_store(&flg[(g * 16 + cg) * 16], fv, __ATOMIC_RELAXED,
                         __HIP_MEMORY_SCOPE_AGENT);
  }
}

extern "C" void kernel_launch(void* const* d_in, const int* in_sizes, int n_in,
                              void* d_out, int out_size, void* d_ws, size_t ws_size,
                              hipStream_t stream) {
  (void)in_sizes; (void)n_in; (void)out_size;
  const float* x = (const float*)d_in[0];
  const void* rstp = (const void*)d_in[1];
  const float* h0 = (const float*)d_in[2];
  const float* c0 = (const float*)d_in[3];
  const float* wih = (const float*)d_in[4];
  const float* whh = (const float*)d_in[5];
  const float* bih = (const float*)d_in[6];
  const float* bhh = (const float*)d_in[7];
  float* y = (float*)d_out;

  if (ws_size < WS_NEED) return;  // diagnosable clean failure

  unsigned* hexw = (unsigned*)((char*)d_ws + HEXW_OFF);
  unsigned* GSEG = (unsigned*)((char*)d_ws + GSEG_OFF);
  unsigned* GCNT = (unsigned*)((char*)d_ws + GCNT_OFF);
  unsigned* flg = (unsigned*)((char*)d_ws + FLG_OFF);
  unsigned* SEGT = (unsigned*)((char*)d_ws + SEGT_OFF);

  // zero tags (tag 0 never used) + flags; ~32 MB, L3-speed
  (void)hipMemsetAsync(d_ws, 0, FLG_OFF + FLG_BYTES, stream);

  seg_setup<<<dim3(1), dim3(512), 0, stream>>>(rstp, GSEG, GCNT, SEGT);

  (void)hipFuncSetAttribute(reinterpret_cast<const void*>(rlstm_seq),
                            hipFuncAttributeMaxDynamicSharedMemorySize, SMEM_BYTES);
  void* args[] = {(void*)&x,    (void*)&h0,  (void*)&c0,   (void*)&whh,
                  (void*)&wih,  (void*)&bih, (void*)&bhh,  (void*)&y,
                  (void*)&hexw, (void*)&flg, (void*)&GSEG, (void*)&GCNT};
  (void)hipLaunchCooperativeKernel((void*)rlstm_seq, dim3(256), dim3(512), args,
                                   SMEM_BYTES, stream);
}

// Round 15
// 1206.545 us; speedup vs baseline: 7.4464x; 1.1288x over previous
//
#include <hip/hip_runtime.h>
#include <math.h>

typedef __attribute__((ext_vector_type(8))) short short8;
typedef __attribute__((ext_vector_type(4))) float f32x4;

#define TSTEPS 1024
#define BATCH  64
#define CDIM   512
#define CAP    256   // segments per group-chunk (ring-row capacity)
#define NPH    4     // ring phases

// ---- workspace layout ----
// HEXW: tagged u32 [16 groups][NPH][CAP rows][512 cols] = 32 MiB
#define HEXW_OFF   0
#define HEXW_BYTES ((size_t)16 * NPH * CAP * 512 * 4)
#define GSEG_OFF   (HEXW_OFF + HEXW_BYTES)
#define GSEG_BYTES ((size_t)65536 * 4)
#define GCNT_OFF   (GSEG_OFF + GSEG_BYTES)
#define GCNT_BYTES (1024 * 4)
#define FLG_OFF    (GCNT_OFF + GCNT_BYTES)
#define FLG_BYTES  (256 * 16 * 4)
#define SEGT_OFF   (FLG_OFF + FLG_BYTES)
#define SEGT_BYTES ((size_t)64 * 1024 * 4)
#define WS_NEED    (SEGT_OFF + SEGT_BYTES)

// ---- main kernel LDS map (dynamic, bytes) ----
// HA dbuf 2x16K @0 ; XA dbuf 2x16K @32768 ; CSEG f32[256][32] @65536 ;
// GC u32[1024] @98304 ; SEGL u32[256] @102400
#define SMEM_BYTES 103424   // > 81920 -> 1 block/CU

__device__ __forceinline__ unsigned short f2bf(float x) {
  unsigned u = __builtin_bit_cast(unsigned, x);
  unsigned r = (u + 0x7FFFu + ((u >> 16) & 1u)) >> 16;
  return (unsigned short)r;
}
__device__ __forceinline__ short8 pack8(float4 lo, float4 hi) {
  short8 r;
  r[0] = (short)f2bf(lo.x); r[1] = (short)f2bf(lo.y);
  r[2] = (short)f2bf(lo.z); r[3] = (short)f2bf(lo.w);
  r[4] = (short)f2bf(hi.x); r[5] = (short)f2bf(hi.y);
  r[6] = (short)f2bf(hi.z); r[7] = (short)f2bf(hi.w);
  return r;
}
__device__ __forceinline__ float sigm(float z) { return 1.0f / (1.0f + __expf(-z)); }
__device__ __forceinline__ float tanh_f(float x) {
  return 2.0f / (1.0f + __expf(-2.0f * x)) - 1.0f;
}
__device__ __forceinline__ void backoff(int rnd) {
  if (rnd == 1) __builtin_amdgcn_s_sleep(1);
  else if (rnd >= 2) __builtin_amdgcn_s_sleep(2);
}
// LDS-only barrier: no vmcnt(0) drain (y/flush stores stay in flight;
// cross-block visibility is tag-certified). Rule-18 fences included.
__device__ __forceinline__ void soft_barrier() {
  __builtin_amdgcn_sched_barrier(0);
  asm volatile("s_waitcnt lgkmcnt(0)" ::: "memory");
  __builtin_amdgcn_s_barrier();
  __builtin_amdgcn_sched_barrier(0);
}

// chunk-boundary only: poll 15 peer flags
__device__ __forceinline__ void pollg(const unsigned* flg, int g, int cg,
                                      unsigned tgt, int lane) {
  const int idx = lane & 15;
  int rnd = 0;
  while (true) {
    unsigned v = (idx == cg)
                     ? 0xffffffffu
                     : __hip_atomic_load(&flg[(g * 16 + idx) * 16],
                                         __ATOMIC_RELAXED, __HIP_MEMORY_SCOPE_AGENT);
    if (__all((int)(v >= tgt))) break;
    backoff(++rnd > 2 ? 2 : rnd);
  }
  asm volatile("" ::: "memory");
}

// ============ kernel 0: segment extraction + counting sort by length desc ====
// GSEG[rank] packed: len(11)<<17 | start(10)<<7 | b(6)<<1 | seed(1).
// Rank p sorted by len desc; group g owns ranks p%16==g. GCNT[r] = #len>r.
__global__ __launch_bounds__(512) void seg_setup(const void* __restrict__ rst,
    unsigned* __restrict__ GSEG, unsigned* __restrict__ GCNT,
    unsigned* __restrict__ SEGT) {
  __shared__ unsigned long long RM[1024];     // per-t batch mask
  __shared__ unsigned long long BM[64][17];   // per-b time mask (16 u64 + pad)
  __shared__ unsigned hist[1025], GCl[1025], cur[1025];
  __shared__ unsigned nsegb[64];
  __shared__ int s_oki, s_okf, s_oddnz;
  const int tid = threadIdx.x, lane = tid & 63, wv = tid >> 6;
  if (tid == 0) { s_oki = 1; s_okf = 1; s_oddnz = 0; }
  __syncthreads();
  {
    int oki = 1, okf = 1, oddnz = 0;
    for (int i = tid; i < 1024; i += 512) {
      unsigned v = ((const unsigned*)rst)[i];
      oki &= (v <= 1u);
      okf &= (v == 0u || v == 0x3F800000u);
      if ((i & 1) && v != 0u) oddnz = 1;
    }
    if (!oki) atomicAnd(&s_oki, 0);
    if (!okf) atomicAnd(&s_okf, 0);
    if (oddnz) atomicOr(&s_oddnz, 1);
  }
  __syncthreads();
  const int mode = s_oki ? (s_oddnz ? 0 : 3) : (s_okf ? 2 : 1);
  for (int tt = wv; tt < 1024; tt += 8) {
    int idx = tt * BATCH + lane;
    bool r;
    if (mode == 0)      r = ((const int*)rst)[idx] != 0;
    else if (mode == 1) r = ((const unsigned char*)rst)[idx] != 0;
    else if (mode == 2) r = ((const float*)rst)[idx] != 0.0f;
    else                r = ((const int*)rst)[2 * idx] != 0;
    unsigned long long bm = __ballot((int)r);
    if (lane == 0) RM[tt] = bm;
  }
  for (int i = tid; i < 1025; i += 512) { hist[i] = 0; cur[i] = 0; }
  __syncthreads();
  // ballot transpose: BM[b][w] bit t' = reset[w*64+t'][b]
  for (int idx = wv; idx < 1024; idx += 8) {
    int b = idx >> 4, w = idx & 15;
    unsigned long long bit = (RM[w * 64 + lane] >> b) & 1ull;
    unsigned long long m = __ballot((int)(bit != 0ull));
    if (lane == 0) BM[b][w] = m;
  }
  __syncthreads();
  if (tid < 64) {
    int b = tid; unsigned cnt = 0; int s = 0;
    unsigned seed0 = (BM[b][0] & 1ull) ? 0u : 1u;
    for (int w = 0; w < 16; ++w) {
      unsigned long long m = BM[b][w];
      if (w == 0) m &= ~1ull;
      while (m) {
        int t = w * 64 + __builtin_ctzll(m);
        m &= m - 1;
        unsigned len = (unsigned)(t - s);
        unsigned sd = (s == 0) ? seed0 : 0u;
        SEGT[b * 1024 + cnt++] =
            (len << 17) | ((unsigned)s << 7) | ((unsigned)b << 1) | sd;
        atomicAdd(&hist[len], 1u);
        s = t;
      }
    }
    { unsigned len = (unsigned)(1024 - s);
      unsigned sd = (s == 0) ? seed0 : 0u;
      SEGT[b * 1024 + cnt++] =
          (len << 17) | ((unsigned)s << 7) | ((unsigned)b << 1) | sd;
      atomicAdd(&hist[len], 1u); }
    nsegb[b] = cnt;
  }
  __syncthreads();
  if (tid == 0) {
    unsigned acc = 0;
    for (int r = 1023; r >= 0; --r) { acc += hist[r + 1]; GCl[r] = acc; }
    GCl[1024] = 0;
  }
  __syncthreads();
  if (tid < 64) {
    int b = tid;
    for (unsigned k = 0; k < nsegb[b]; ++k) {
      unsigned v = SEGT[b * 1024 + k];
      unsigned len = v >> 17;
      unsigned p = GCl[len] + atomicAdd(&cur[len], 1u);
      GSEG[p] = v;
    }
  }
  __syncthreads();
  for (int i = tid; i < 1024; i += 512) GCNT[i] = GCl[i];
}

// ============ kernel 1: depth-parallel LSTM, tagged 4-phase ring exchange ====
// Per tile: write prefetched x -> poll/stage h -> soft barrier (lgkm only) ->
// issue next tile's x loads -> 32 MFMA -> 4-shfl gate transpose -> cell ->
// per-lane tagged flush. x gather + store drains are OFF the critical path.
__global__ __launch_bounds__(512, 1) void rlstm_seq(
    const float* __restrict__ x, const float* __restrict__ h0,
    const float* __restrict__ c0, const float* __restrict__ whh,
    const float* __restrict__ wih, const float* __restrict__ bih,
    const float* __restrict__ bhh, float* __restrict__ y,
    unsigned* __restrict__ hexw, unsigned* __restrict__ flg,
    const unsigned* __restrict__ GSEG, const unsigned* __restrict__ GCNT) {
  extern __shared__ __align__(16) char smem[];
  float* CSEG = (float*)(smem + 65536);
  unsigned* GC = (unsigned*)(smem + 98304);
  unsigned* SEGL = (unsigned*)(smem + 102400);

  const int tid = threadIdx.x, bid = blockIdx.x;
  const int g = bid >> 4, cg = bid & 15;
  const int lane = tid & 63, wv = tid >> 6;
  const int grp = lane >> 4, lr = lane & 15;
  const int gt = lr >> 2, j = lr & 3;
  const int lcol = wv * 4 + j;
  const int cglob = cg * 32 + lcol;
  const int nglob = gt * CDIM + cglob;
  const int srow = 2 * wv + (lane >> 5);
  const int wcol = lane & 31;
  const int swz = (srow & 7) << 4;

  // both weight slices register-resident: 128 VGPR/wave
  short8 wfrag[16], wfrag2[16];
#pragma unroll
  for (int kk = 0; kk < 16; ++kk) {
    const float* s = whh + (size_t)nglob * CDIM + kk * 32 + grp * 8;
    float4 lo = *(const float4*)s, hi = *(const float4*)(s + 4);
    wfrag[kk] = pack8(lo, hi);
    const float* s2 = wih + (size_t)nglob * CDIM + kk * 32 + grp * 8;
    float4 lo2 = *(const float4*)s2, hi2 = *(const float4*)(s2 + 4);
    wfrag2[kk] = pack8(lo2, hi2);
  }
  const float bsum = bih[nglob] + bhh[nglob];

  for (int i = tid; i < 1024; i += 512) GC[i] = GCNT[i];
  __syncthreads();

  const unsigned G0 = GC[0];
  const unsigned totg = (G0 > (unsigned)g) ? ((G0 - g + 15u) >> 4) : 0u;
  const int nchunks = (int)((totg + CAP - 1) / CAP);
  unsigned tg = 0, fv = 0;
  float4 xv[4] = {{0,0,0,0},{0,0,0,0},{0,0,0,0},{0,0,0,0}};  // x prefetch regs

  for (int chunk = 0; chunk < nchunks; ++chunk) {
    const unsigned cb = (unsigned)chunk * CAP;
    int M0;
    { unsigned t2 = totg;
      M0 = (t2 > cb) ? (int)((t2 - cb > CAP) ? CAP : (t2 - cb)) : 0; }
    if (M0 == 0) break;
    if (chunk > 0) pollg(flg, g, cg, fv, lane);  // peers exited prior chunk

    ++tg;  // seed tag (consumed by round 0)
    // ---- seed phase 0 + CSEG + SEGL ----
    for (int i = tid >> 4; i < M0; i += 32) {
      int c2 = (tid & 15) * 2;
      unsigned sv = GSEG[(size_t)(cb + i) * 16 + g];
      if ((tid & 15) == 0) SEGL[i] = sv;
      int b = (sv >> 1) & 63;
      float ha = 0.f, hb = 0.f, ca = 0.f, cbv = 0.f;
      if (sv & 1u) {
        const float* hp = h0 + (size_t)b * CDIM + cg * 32 + c2;
        ha = hp[0]; hb = hp[1];
        const float* cp = c0 + (size_t)b * CDIM + cg * 32 + c2;
        ca = cp[0]; cbv = cp[1];
      }
      CSEG[i * 32 + c2] = ca; CSEG[i * 32 + c2 + 1] = cbv;
      unsigned lo = ((unsigned)f2bf(ha) << 16) | tg;
      unsigned hi2 = ((unsigned)f2bf(hb) << 16) | tg;
      unsigned long long w = ((unsigned long long)hi2 << 32) | lo;
      __hip_atomic_store((unsigned long long*)hexw +
                             ((size_t)(g * NPH + 0) * CAP + i) * 256 + cg * 16 +
                             (tid & 15),
                         w, __ATOMIC_RELAXED, __HIP_MEMORY_SCOPE_AGENT);
    }
    __syncthreads();  // SEGL/CSEG ready

    // prologue: issue x loads for (round 0, tile 0)
    { int i = srow;
      if (i < M0) {
        unsigned sv = SEGL[i];
        int b = (sv >> 1) & 63, s0 = (sv >> 7) & 1023;
        const float* xr = x + ((size_t)s0 * BATCH + b) * CDIM;
        xv[0] = *(const float4*)(xr + wcol * 8);
        xv[1] = *(const float4*)(xr + wcol * 8 + 4);
        xv[2] = *(const float4*)(xr + (wcol + 32) * 8);
        xv[3] = *(const float4*)(xr + (wcol + 32) * 8 + 4);
      }
    }

    // ---- depth rounds ----
    for (int r = 0;; ++r) {
      if (r >= 1024) break;
      int M;
      { unsigned Gr = GC[r];
        unsigned t2 = (Gr > (unsigned)g) ? ((Gr - g + 15u) >> 4) : 0u;
        M = (t2 > cb) ? (int)((t2 - cb > CAP) ? CAP : (t2 - cb)) : 0; }
      if (M == 0) break;
      int Mn = 0;
      if (r + 1 < 1024) {
        unsigned Gn = GC[r + 1];
        unsigned t2 = (Gn > (unsigned)g) ? ((Gn - g + 15u) >> 4) : 0u;
        Mn = (t2 > cb) ? (int)((t2 - cb > CAP) ? CAP : (t2 - cb)) : 0;
      }
      const int ph = r & (NPH - 1), phw = (r + 1) & (NPH - 1);
      const unsigned wtg = tg + 1;
      unsigned* const wbase = hexw + (size_t)(g * NPH + phw) * CAP * 512;

      for (int i0 = 0; i0 < M; i0 += 16) {
        const int p = ((i0 >> 4) + r) & 1;
        char* habuf = smem + p * 16384;
        char* xabuf = smem + 32768 + p * 16384;

        // write prefetched x regs to LDS (loads issued ~1 tile ago)
        { int i = i0 + srow;
          if (i < M) {
            *(short8*)(xabuf + srow * 1024 + ((wcol * 16) ^ swz)) =
                pack8(xv[0], xv[1]);
            *(short8*)(xabuf + srow * 1024 + (((wcol + 32) * 16) ^ swz)) =
                pack8(xv[2], xv[3]);
          }
        }
        // poll + stage h_prev tile (tagged words ARE the handshake)
        { int i = i0 + srow;
          if (i < M) {
            const unsigned long long* hq = (const unsigned long long*)hexw +
                ((size_t)(g * NPH + ph) * CAP + i) * 256;
            unsigned long long v8[8];
            unsigned pn = 0xffu;
            int rnd = 0;
            do {
              backoff(rnd > 2 ? 2 : rnd);
              ++rnd;
#pragma unroll
              for (int k = 0; k < 8; ++k)
                if (pn & (1u << k))
                  v8[k] = __hip_atomic_load(hq + wcol + 32 * k, __ATOMIC_RELAXED,
                                            __HIP_MEMORY_SCOPE_AGENT);
              unsigned np = 0;
#pragma unroll
              for (int k = 0; k < 8; ++k) {
                unsigned lo = (unsigned)v8[k];
                unsigned hi = (unsigned)(v8[k] >> 32);
                if (((lo ^ tg) | (hi ^ tg)) & 0xffffu) np |= 1u << k;
              }
              pn = np;
            } while (__any((int)pn));
#pragma unroll
            for (int k = 0; k < 8; ++k) {
              unsigned lo = (unsigned)v8[k];
              unsigned hi = (unsigned)(v8[k] >> 32);
              unsigned pk = (lo >> 16) | (hi & 0xffff0000u);
              int m = wcol + 32 * k;
              *(unsigned*)(habuf + srow * 1024 + ((m * 4) ^ swz)) = pk;
            }
          }
        }
        soft_barrier();  // LDS-only: y/flush stores stay in flight

        // issue x loads for NEXT tile (hidden under MFMA + next poll)
        { int nii = i0 + 16, nbound = M, nr = r;
          if (nii >= M) { nii = 0; nbound = Mn; nr = r + 1; }
          int i = nii + srow;
          if (i < nbound) {
            unsigned sv = SEGL[i];
            int b = (sv >> 1) & 63, s0 = (sv >> 7) & 1023;
            const float* xr = x + ((size_t)(s0 + nr) * BATCH + b) * CDIM;
            xv[0] = *(const float4*)(xr + wcol * 8);
            xv[1] = *(const float4*)(xr + wcol * 8 + 4);
            xv[2] = *(const float4*)(xr + (wcol + 32) * 8);
            xv[3] = *(const float4*)(xr + (wcol + 32) * 8 + 4);
          }
        }

        // recurrent + input GEMMs: dual chains each
        f32x4 h0a = {0.f,0.f,0.f,0.f}, h1a = {0.f,0.f,0.f,0.f};
        f32x4 x0a = {0.f,0.f,0.f,0.f}, x1a = {0.f,0.f,0.f,0.f};
#pragma unroll
        for (int kk = 0; kk < 16; ++kk) {
          const int aoff = ((kk * 64 + grp * 16) ^ ((lr & 7) << 4));
          short8 a = *(const short8*)(habuf + lr * 1024 + aoff);
          short8 ax = *(const short8*)(xabuf + lr * 1024 + aoff);
          if (kk & 1) {
            h1a = __builtin_amdgcn_mfma_f32_16x16x32_bf16(a, wfrag[kk], h1a, 0, 0, 0);
            x1a = __builtin_amdgcn_mfma_f32_16x16x32_bf16(ax, wfrag2[kk], x1a, 0, 0, 0);
          } else {
            h0a = __builtin_amdgcn_mfma_f32_16x16x32_bf16(a, wfrag[kk], h0a, 0, 0, 0);
            x0a = __builtin_amdgcn_mfma_f32_16x16x32_bf16(ax, wfrag2[kk], x0a, 0, 0, 0);
          }
        }
        f32x4 acc = (h0a + h1a) + (x0a + x1a);

        // ---- 4x4 gate transpose across gt-lanes (4 shfl), then one cell ----
        float a0 = acc[0] + bsum, a1 = acc[1] + bsum;
        float a2 = acc[2] + bsum, a3 = acc[3] + bsum;
        const int b0 = gt & 1, b1 = (gt >> 1) & 1;
        float sA0 = b0 ? a0 : a1;
        float sA1 = b0 ? a2 : a3;
        float rA0 = __shfl_xor(sA0, 4);
        float rA1 = __shfl_xor(sA1, 4);
        float k0 = b0 ? a1 : a0;
        float k1 = b0 ? a3 : a2;
        float sB0 = b1 ? k0 : k1;
        float sB1 = b1 ? rA0 : rA1;
        float rB0 = __shfl_xor(sB0, 8);
        float rB1 = __shfl_xor(sB1, 8);
        float m0 = b1 ? k1 : k0;
        float m1 = b1 ? rA1 : rA0;
        float gi = (gt == 0) ? m0 : (gt == 1) ? m1 : (gt == 2) ? rB0 : rB1;
        float gf = (gt == 1) ? m0 : (gt == 0) ? m1 : (gt == 3) ? rB0 : rB1;
        float gg = (gt == 2) ? m0 : (gt == 3) ? m1 : (gt == 0) ? rB0 : rB1;
        float go = (gt == 3) ? m0 : (gt == 2) ? m1 : (gt == 1) ? rB0 : rB1;

        const int i = i0 + grp * 4 + gt;    // this lane's row
        if (i < M) {
          float cprev = CSEG[i * 32 + lcol];
          float cn = sigm(gf) * cprev + sigm(gi) * tanh_f(gg);
          CSEG[i * 32 + lcol] = cn;
          float hsel = sigm(go) * tanh_f(cn);
          if (i < Mn) {
            unsigned w = ((unsigned)f2bf(hsel) << 16) | wtg;
            __hip_atomic_store(wbase + (size_t)i * 512 + cglob, w,
                               __ATOMIC_RELAXED, __HIP_MEMORY_SCOPE_AGENT);
          }
          unsigned sv = SEGL[i];
          int rowm = (int)((((sv >> 7) & 1023) + r) * BATCH + ((sv >> 1) & 63));
          y[(size_t)rowm * CDIM + cglob] = hsel;
        }
      }
      ++tg;  // next round's input tag
    }

    // chunk done: post flag so peers may reuse phase 0 for next chunk's seed
    ++fv;
    asm volatile("s_waitcnt vmcnt(0)" ::: "memory");
    __syncthreads();
    if (tid == 0)
      __hip_atomic_store(&flg[(g * 16 + cg) * 16], fv, __ATOMIC_RELAXED,
                         __HIP_MEMORY_SCOPE_AGENT);
  }
}

extern "C" void kernel_launch(void* const* d_in, const int* in_sizes, int n_in,
                              void* d_out, int out_size, void* d_ws, size_t ws_size,
                              hipStream_t stream) {
  (void)in_sizes; (void)n_in; (void)out_size;
  const float* x = (const float*)d_in[0];
  const void* rstp = (const void*)d_in[1];
  const float* h0 = (const float*)d_in[2];
  const float* c0 = (const float*)d_in[3];
  const float* wih = (const float*)d_in[4];
  const float* whh = (const float*)d_in[5];
  const float* bih = (const float*)d_in[6];
  const float* bhh = (const float*)d_in[7];
  float* y = (float*)d_out;

  if (ws_size < WS_NEED) return;  // diagnosable clean failure

  unsigned* hexw = (unsigned*)((char*)d_ws + HEXW_OFF);
  unsigned* GSEG = (unsigned*)((char*)d_ws + GSEG_OFF);
  unsigned* GCNT = (unsigned*)((char*)d_ws + GCNT_OFF);
  unsigned* flg = (unsigned*)((char*)d_ws + FLG_OFF);
  unsigned* SEGT = (unsigned*)((char*)d_ws + SEGT_OFF);

  // zero tags (tag 0 never used) + flags; ~32 MB, L3-speed
  (void)hipMemsetAsync(d_ws, 0, FLG_OFF + FLG_BYTES, stream);

  seg_setup<<<dim3(1), dim3(512), 0, stream>>>(rstp, GSEG, GCNT, SEGT);

  (void)hipFuncSetAttribute(reinterpret_cast<const void*>(rlstm_seq),
                            hipFuncAttributeMaxDynamicSharedMemorySize, SMEM_BYTES);
  void* args[] = {(void*)&x,    (void*)&h0,  (void*)&c0,   (void*)&whh,
                  (void*)&wih,  (void*)&bih, (void*)&bhh,  (void*)&y,
                  (void*)&hexw, (void*)&flg, (void*)&GSEG, (void*)&GCNT};
  (void)hipLaunchCooperativeKernel((void*)rlstm_seq, dim3(256), dim3(512), args,
                                   SMEM_BYTES, stream);
}